// Round 3
// baseline (5312.992 us; speedup 1.0000x reference)
//
#include <hip/hip_runtime.h>
#include <math.h>

#define NN 100000
#define EE 1600000
#define FF 256
#define CC 128
#define NFD 193

__device__ __forceinline__ float wave_sum(float v) {
    #pragma unroll
    for (int o = 32; o > 0; o >>= 1) v += __shfl_xor(v, o, 64);
    return v;
}
__device__ __forceinline__ float wave_max(float v) {
    #pragma unroll
    for (int o = 32; o > 0; o >>= 1) v = fmaxf(v, __shfl_xor(v, o, 64));
    return v;
}

// ---- energy = logsumexp over C=128, one wave per row ----
__global__ void k_energy(const float* __restrict__ logits, float* __restrict__ e) {
    int wid = (int)((blockIdx.x * blockDim.x + threadIdx.x) >> 6);
    int lane = threadIdx.x & 63;
    if (wid >= NN) return;
    const float* rowp = logits + (size_t)wid * CC;
    float a = rowp[lane], b = rowp[lane + 64];
    float m = wave_max(fmaxf(a, b));
    float s = expf(a - m) + expf(b - m);
    s = wave_sum(s);
    if (lane == 0) e[wid] = m + logf(s);
}

__global__ void k_deg(const int* __restrict__ col, float* __restrict__ deg) {
    int i = blockIdx.x * blockDim.x + threadIdx.x;
    if (i < EE) atomicAdd(&deg[col[i]], 1.0f);
}

__global__ void k_prop(const int* __restrict__ row, const int* __restrict__ col,
                       const float* __restrict__ e, const float* __restrict__ deg,
                       float* __restrict__ agg) {
    int i = blockIdx.x * blockDim.x + threadIdx.x;
    if (i >= EE) return;
    int c = col[i];
    float d = deg[c];
    if (d > 0.f) atomicAdd(&agg[c], e[row[i]] / d);
}

__global__ void k_combine(float* __restrict__ e, const float* __restrict__ agg) {
    int i = blockIdx.x * blockDim.x + threadIdx.x;
    if (i < NN) e[i] = 0.5f * e[i] + 0.5f * agg[i];
}

// ---- reduction: sum (meanptr==null) or sum of squared deviations ----
__global__ void k_reduce(const float* __restrict__ e, float* __restrict__ out,
                         const float* __restrict__ meanptr) {
    float mean = meanptr ? (*meanptr) / (float)NN : 0.0f;
    float s = 0.f;
    for (int i = blockIdx.x * blockDim.x + threadIdx.x; i < NN; i += gridDim.x * blockDim.x) {
        if (meanptr) { float v = e[i] - mean; s += v * v; }
        else s += e[i];
    }
    s = wave_sum(s);
    __shared__ float ls[4];
    int lane = threadIdx.x & 63, w = threadIdx.x >> 6;
    if (lane == 0) ls[w] = s;
    __syncthreads();
    if (threadIdx.x == 0) atomicAdd(out, ls[0] + ls[1] + ls[2] + ls[3]);
}

__global__ void k_standardize(float* __restrict__ e, const float* __restrict__ scal) {
    float mean = scal[0] / (float)NN;
    float var = scal[1] / (float)(NN - 1);
    float inv = 1.0f / (sqrtf(var) + 1e-6f);
    int i = blockIdx.x * blockDim.x + threadIdx.x;
    if (i < NN) e[i] = (e[i] - mean) * inv;
}

// ---- tiny energy-branch MLP: 1 -> 16 relu -> 8 (chunked) ----
__global__ void k_pe(const float* __restrict__ e, const float* __restrict__ w1,
                     const float* __restrict__ b1, const float* __restrict__ w2,
                     const float* __restrict__ b2, float* __restrict__ pe, int M) {
    int i = blockIdx.x * blockDim.x + threadIdx.x;
    if (i >= M) return;
    float ev = e[i];
    float h[16];
    #pragma unroll
    for (int j = 0; j < 16; ++j) h[j] = fmaxf(ev * w1[j] + b1[j], 0.f);
    #pragma unroll
    for (int k = 0; k < 8; ++k) {
        float s = b2[k];
        #pragma unroll
        for (int j = 0; j < 16; ++j) s += h[j] * w2[j * 8 + k];
        pe[(size_t)i * 8 + k] = s;
    }
}

__global__ void k_dis(const float* __restrict__ deg, float* __restrict__ dis) {
    int i = blockIdx.x * blockDim.x + threadIdx.x;
    if (i < NN) dis[i] = 1.0f / sqrtf(deg[i] + 1.0f);
}

// ---- g init: bias + self-loop contribution (global, all N) ----
__global__ void k_ginit(const float* __restrict__ h, const float* __restrict__ dis,
                        const float* __restrict__ b, float* __restrict__ g) {
    int t = blockIdx.x * blockDim.x + threadIdx.x;
    if (t >= NN * CC) return;
    int i = t >> 7, c = t & 127;
    float d = dis[i];
    g[t] = b[c] + d * d * h[t];
}

// ---- GCN edge aggregation, one wave per edge (128 channels = 2/lane) ----
__global__ void k_gedge(const int* __restrict__ row, const int* __restrict__ col,
                        const float* __restrict__ dis, const float* __restrict__ h,
                        float* __restrict__ g) {
    int wid = (int)((blockIdx.x * blockDim.x + threadIdx.x) >> 6);
    int lane = threadIdx.x & 63;
    if (wid >= EE) return;
    int r = row[wid], c = col[wid];
    float nrm = dis[r] * dis[c];
    size_t hb = (size_t)r * CC, gb = (size_t)c * CC;
    atomicAdd(&g[gb + lane], nrm * h[hb + lane]);
    atomicAdd(&g[gb + lane + 64], nrm * h[hb + lane + 64]);
}

// ---- generic f32 tiled GEMM: C = act(A[MxK] @ W[KxN] + bias) ----
#define BM 64
#define BN 64
#define BK 32
__global__ __launch_bounds__(256) void k_gemm(const float* __restrict__ A,
                                              const float* __restrict__ W,
                                              const float* __restrict__ bias,
                                              float* __restrict__ C,
                                              int M, int K, int N, int act) {
    __shared__ float As[BM][BK + 1];
    __shared__ float Ws[BK][BN];
    int t = threadIdx.x;
    int tx = t & 15, ty = t >> 4;
    int rowBase = blockIdx.y * BM;
    int colBase = blockIdx.x * BN;
    float acc[4][4] = {};
    for (int kk = 0; kk < K; kk += BK) {
        #pragma unroll
        for (int l = 0; l < 8; ++l) {
            int idx = l * 256 + t;
            int r = idx >> 5, c = idx & 31;
            int gr = rowBase + r, gc = kk + c;
            As[r][c] = (gr < M && gc < K) ? A[(size_t)gr * K + gc] : 0.f;
        }
        #pragma unroll
        for (int l = 0; l < 8; ++l) {
            int idx = l * 256 + t;
            int r = idx >> 6, c = idx & 63;
            int gr = kk + r, gc = colBase + c;
            Ws[r][c] = (gr < K && gc < N) ? W[(size_t)gr * N + gc] : 0.f;
        }
        __syncthreads();
        #pragma unroll
        for (int k = 0; k < BK; ++k) {
            float a[4], b[4];
            #pragma unroll
            for (int i = 0; i < 4; ++i) a[i] = As[ty * 4 + i][k];
            #pragma unroll
            for (int j = 0; j < 4; ++j) b[j] = Ws[k][tx * 4 + j];
            #pragma unroll
            for (int i = 0; i < 4; ++i)
                #pragma unroll
                for (int j = 0; j < 4; ++j)
                    acc[i][j] += a[i] * b[j];
        }
        __syncthreads();
    }
    #pragma unroll
    for (int i = 0; i < 4; ++i) {
        int gr = rowBase + ty * 4 + i;
        if (gr >= M) continue;
        #pragma unroll
        for (int j = 0; j < 4; ++j) {
            int gc = colBase + tx * 4 + j;
            if (gc >= N) continue;
            float v = acc[i][j];
            if (bias) v += bias[gc];
            if (act == 1) v = fmaxf(v, 0.f);
            C[(size_t)gr * N + gc] = v;
        }
    }
}

// ---- attention fusion, one wave per node (chunked) ----
__global__ void k_fuse(float* __restrict__ xt, const float* __restrict__ lt,
                       const float* __restrict__ et, const float* __restrict__ aw,
                       const float* __restrict__ ab, int M) {
    int wid = (int)((blockIdx.x * blockDim.x + threadIdx.x) >> 6);
    int lane = threadIdx.x & 63;
    if (wid >= M) return;
    size_t base = (size_t)wid * NFD;
    float xv[4], lv[4], ev[4];
    float dx = 0.f, dl = 0.f, de = 0.f;
    #pragma unroll
    for (int q = 0; q < 4; ++q) {
        int j = q * 64 + lane;
        bool ok = j < NFD;
        float awv = ok ? aw[j] : 0.f;
        xv[q] = ok ? xt[base + j] : 0.f;
        lv[q] = ok ? lt[base + j] : 0.f;
        ev[q] = ok ? et[base + j] : 0.f;
        dx += xv[q] * awv; dl += lv[q] * awv; de += ev[q] * awv;
    }
    dx = wave_sum(dx); dl = wave_sum(dl); de = wave_sum(de);
    float abv = ab[0];
    float sx = 1.f / (1.f + expf(-(dx + abv)));
    float sl = 1.f / (1.f + expf(-(dl + abv)));
    float se = 1.f / (1.f + expf(-(de + abv)));
    float inv = 1.f / (sx + sl + se);
    #pragma unroll
    for (int q = 0; q < 4; ++q) {
        int j = q * 64 + lane;
        if (j < NFD) xt[base + j] = (sx * xv[q] + sl * lv[q] + se * ev[q]) * inv;
    }
}

// ---- final 128->1 + sigmoid, one wave per row (chunked) ----
__global__ void k_pred(const float* __restrict__ h2, const float* __restrict__ w3,
                       const float* __restrict__ b3, float* __restrict__ pred, int M) {
    int wid = (int)((blockIdx.x * blockDim.x + threadIdx.x) >> 6);
    int lane = threadIdx.x & 63;
    if (wid >= M) return;
    const float* r = h2 + (size_t)wid * CC;
    float s = r[lane] * w3[lane] + r[lane + 64] * w3[lane + 64];
    s = wave_sum(s);
    if (lane == 0) pred[wid] = 1.f / (1.f + expf(-(s + b3[0])));
}

__global__ void k_gather(const float* __restrict__ pred, const int* __restrict__ mask,
                         float* __restrict__ out, int n) {
    int i = blockIdx.x * blockDim.x + threadIdx.x;
    if (i < n) out[i] = pred[mask[i]];
}

static inline void gemm(const float* A, const float* W, const float* bias, float* C,
                        int M, int K, int N, int act, hipStream_t s) {
    dim3 grid((N + BN - 1) / BN, (M + BM - 1) / BM);
    k_gemm<<<grid, 256, 0, s>>>(A, W, bias, C, M, K, N, act);
}

extern "C" void kernel_launch(void* const* d_in, const int* in_sizes, int n_in,
                              void* d_out, int out_size, void* d_ws, size_t ws_size,
                              hipStream_t stream) {
    const float* logits = (const float*)d_in[0];
    const float* x      = (const float*)d_in[1];
    const int*   eidx   = (const int*)d_in[2];
    const int*   mask   = (const int*)d_in[3];
    const float* fp_w1 = (const float*)d_in[4];
    const float* fp_b1 = (const float*)d_in[5];
    const float* fp_w2 = (const float*)d_in[6];
    const float* fp_b2 = (const float*)d_in[7];
    const float* ep_w1 = (const float*)d_in[8];
    const float* ep_b1 = (const float*)d_in[9];
    const float* ep_w2 = (const float*)d_in[10];
    const float* ep_b2 = (const float*)d_in[11];
    const float* lp_w1 = (const float*)d_in[12];
    const float* lp_b1 = (const float*)d_in[13];
    const float* lp_w2 = (const float*)d_in[14];
    const float* lp_b2 = (const float*)d_in[15];
    const float* gcn_w = (const float*)d_in[16];
    const float* gcn_b = (const float*)d_in[17];
    const float* gt_w  = (const float*)d_in[18];
    const float* gt_b  = (const float*)d_in[19];
    const float* af_xw = (const float*)d_in[20];
    const float* af_xb = (const float*)d_in[21];
    const float* af_lw = (const float*)d_in[22];
    const float* af_lb = (const float*)d_in[23];
    const float* af_ew = (const float*)d_in[24];
    const float* af_eb = (const float*)d_in[25];
    const float* af_aw = (const float*)d_in[26];
    const float* af_ab = (const float*)d_in[27];
    const float* fu_w1 = (const float*)d_in[28];
    const float* fu_b1 = (const float*)d_in[29];
    const float* fu_w2 = (const float*)d_in[30];
    const float* fu_b2 = (const float*)d_in[31];
    const float* fu_w3 = (const float*)d_in[32];
    const float* fu_b3 = (const float*)d_in[33];
    const int* row = eidx;
    const int* col = eidx + EE;
    float* out = (float*)d_out;

    // ---- workspace-adaptive layout ----
    // Fixed global buffers (~104 MB). Everything else lives in a chunk area
    // whose row-count CH adapts to whatever ws_size the harness provides.
    float* ws = (float*)d_ws;
    size_t o = 0;
    float* e_   = ws + o; o += NN;
    float* degv = ws + o; o += NN;
    float* agg  = ws + o; o += NN;   // BP agg; later pred
    float* dis  = ws + o; o += NN;
    float* scal = ws + o; o += 16;
    float* h    = ws + o; o += (size_t)NN * CC;   // pre-aggregation GCN features
    float* g    = ws + o; o += (size_t)NN * CC;   // aggregated GCN output
    size_t fixed = o;

    // chunk area: 1354 floats per row
    //   cb0 [0,512CH)    : fp hidden | gx(256CH) + xt(193CH @ +256CH)
    //   cb1 [512,768)CH  : px | h1
    //   cb2 [768,896)CH  : lp hidden | h2
    //   cb3 [896,960)CH  : pl
    //   cb4 [960,968)CH  : pe
    //   cb5 [968,1161)CH : lt
    //   cb6 [1161,1354)CH: et
    const size_t SROW = 1354;
    size_t avail = ws_size / sizeof(float);
    size_t rem = (avail > fixed) ? (avail - fixed) : 0;
    size_t chq = rem / SROW;
    int CH = (chq >= (size_t)NN) ? NN : (int)chq;
    if (CH < 1) CH = 1;
    float* cb = ws + fixed;
    int nch = (NN + CH - 1) / CH;

    hipMemsetAsync(degv, 0, NN * sizeof(float), stream);
    hipMemsetAsync(scal, 0, 16 * sizeof(float), stream);

    // ---- energy + propagation + standardize ----
    k_energy<<<(NN + 3) / 4, 256, 0, stream>>>(logits, e_);
    k_deg<<<(EE + 255) / 256, 256, 0, stream>>>(col, degv);
    for (int it = 0; it < 2; ++it) {
        hipMemsetAsync(agg, 0, NN * sizeof(float), stream);
        k_prop<<<(EE + 255) / 256, 256, 0, stream>>>(row, col, e_, degv, agg);
        k_combine<<<(NN + 255) / 256, 256, 0, stream>>>(e_, agg);
    }
    k_reduce<<<256, 256, 0, stream>>>(e_, &scal[0], nullptr);
    k_reduce<<<256, 256, 0, stream>>>(e_, &scal[1], &scal[0]);
    k_standardize<<<(NN + 255) / 256, 256, 0, stream>>>(e_, scal);
    k_dis<<<(NN + 255) / 256, 256, 0, stream>>>(degv, dis);

    // ---- Phase A (chunked): fp MLP -> px -> h = px @ gcn_w ----
    for (int c = 0; c < nch; ++c) {
        int base = c * CH;
        int m = (NN - base < CH) ? (NN - base) : CH;
        float* hid = cb;                          // 512*CH
        float* px  = cb + (size_t)512 * CH;       // 256*CH
        gemm(x + (size_t)base * FF, fp_w1, fp_b1, hid, m, 256, 512, 1, stream);
        gemm(hid, fp_w2, fp_b2, px, m, 512, 256, 0, stream);
        gemm(px, gcn_w, nullptr, h + (size_t)base * CC, m, 256, 128, 0, stream);
    }

    // ---- GCN aggregation (global) ----
    k_ginit<<<((size_t)NN * CC + 255) / 256, 256, 0, stream>>>(h, dis, gcn_b, g);
    k_gedge<<<(EE * 64) / 256, 256, 0, stream>>>(row, col, dis, h, g);

    // ---- Phase B (chunked): lp MLP, pe, gx->xt, lt, et, fuse, fusion MLP, pred ----
    for (int c = 0; c < nch; ++c) {
        int base = c * CH;
        int m = (NN - base < CH) ? (NN - base) : CH;
        float* gx  = cb;
        float* xt  = cb + (size_t)256 * CH;
        float* h1  = cb + (size_t)512 * CH;
        float* lph = cb + (size_t)768 * CH;
        float* h2  = cb + (size_t)768 * CH;       // reuses lph after it dies
        float* pl  = cb + (size_t)896 * CH;
        float* pec = cb + (size_t)960 * CH;
        float* lt  = cb + (size_t)968 * CH;
        float* et  = cb + (size_t)1161 * CH;

        gemm(logits + (size_t)base * CC, lp_w1, lp_b1, lph, m, 128, 128, 1, stream);
        gemm(lph, lp_w2, lp_b2, pl, m, 128, 64, 0, stream);
        k_pe<<<(m + 255) / 256, 256, 0, stream>>>(e_ + base, ep_w1, ep_b1, ep_w2, ep_b2, pec, m);

        gemm(g + (size_t)base * CC, gt_w, gt_b, gx, m, 128, 256, 0, stream);
        gemm(gx, af_xw, af_xb, xt, m, 256, NFD, 0, stream);
        gemm(pl, af_lw, af_lb, lt, m, 64, NFD, 0, stream);
        gemm(pec, af_ew, af_eb, et, m, 8, NFD, 0, stream);
        k_fuse<<<(m + 3) / 4, 256, 0, stream>>>(xt, lt, et, af_aw, af_ab, m);

        gemm(xt, fu_w1, fu_b1, h1, m, NFD, 256, 1, stream);
        gemm(h1, fu_w2, fu_b2, h2, m, 256, 128, 1, stream);
        k_pred<<<(m + 3) / 4, 256, 0, stream>>>(h2, fu_w3, fu_b3, agg + base, m);
    }

    k_gather<<<(out_size + 255) / 256, 256, 0, stream>>>(agg, mask, out, out_size);
}

// Round 8
// 1915.536 us; speedup vs baseline: 2.7736x; 2.7736x over previous
//
#include <hip/hip_runtime.h>
#include <math.h>

#define NN 100000
#define EE 1600000
#define FF 256
#define CC 128
#define NFD 193
#define NFP 200   // padded NF stride (keeps bf16 vector loads 16B-aligned)

typedef __attribute__((ext_vector_type(8))) short short8;
typedef __attribute__((ext_vector_type(4))) float f32x4;

__device__ __forceinline__ unsigned short f2b(float f) {
    unsigned u = __float_as_uint(f);
    u += 0x7FFF + ((u >> 16) & 1);   // round-to-nearest-even
    return (unsigned short)(u >> 16);
}

__device__ __forceinline__ float wave_sum(float v) {
    #pragma unroll
    for (int o = 32; o > 0; o >>= 1) v += __shfl_xor(v, o, 64);
    return v;
}
__device__ __forceinline__ float wave_max(float v) {
    #pragma unroll
    for (int o = 32; o > 0; o >>= 1) v = fmaxf(v, __shfl_xor(v, o, 64));
    return v;
}

// ---- energy = logsumexp over C=128, one wave per row ----
__global__ void k_energy(const float* __restrict__ logits, float* __restrict__ e) {
    int wid = (int)((blockIdx.x * blockDim.x + threadIdx.x) >> 6);
    int lane = threadIdx.x & 63;
    if (wid >= NN) return;
    const float* rowp = logits + (size_t)wid * CC;
    float a = rowp[lane], b = rowp[lane + 64];
    float m = wave_max(fmaxf(a, b));
    float s = expf(a - m) + expf(b - m);
    s = wave_sum(s);
    if (lane == 0) e[wid] = m + logf(s);
}

__global__ void k_deg(const int* __restrict__ col, float* __restrict__ deg) {
    int i = blockIdx.x * blockDim.x + threadIdx.x;
    if (i < EE) atomicAdd(&deg[col[i]], 1.0f);
}

__global__ void k_prop(const int* __restrict__ row, const int* __restrict__ col,
                       const float* __restrict__ e, const float* __restrict__ deg,
                       float* __restrict__ agg) {
    int i = blockIdx.x * blockDim.x + threadIdx.x;
    if (i >= EE) return;
    int c = col[i];
    float d = deg[c];
    if (d > 0.f) atomicAdd(&agg[c], e[row[i]] / d);
}

__global__ void k_combine(float* __restrict__ e, const float* __restrict__ agg) {
    int i = blockIdx.x * blockDim.x + threadIdx.x;
    if (i < NN) e[i] = 0.5f * e[i] + 0.5f * agg[i];
}

__global__ void k_reduce(const float* __restrict__ e, float* __restrict__ out,
                         const float* __restrict__ meanptr) {
    float mean = meanptr ? (*meanptr) / (float)NN : 0.0f;
    float s = 0.f;
    for (int i = blockIdx.x * blockDim.x + threadIdx.x; i < NN; i += gridDim.x * blockDim.x) {
        if (meanptr) { float v = e[i] - mean; s += v * v; }
        else s += e[i];
    }
    s = wave_sum(s);
    __shared__ float ls[4];
    int lane = threadIdx.x & 63, w = threadIdx.x >> 6;
    if (lane == 0) ls[w] = s;
    __syncthreads();
    if (threadIdx.x == 0) atomicAdd(out, ls[0] + ls[1] + ls[2] + ls[3]);
}

__global__ void k_standardize(float* __restrict__ e, const float* __restrict__ scal) {
    float mean = scal[0] / (float)NN;
    float var = scal[1] / (float)(NN - 1);
    float inv = 1.0f / (sqrtf(var) + 1e-6f);
    int i = blockIdx.x * blockDim.x + threadIdx.x;
    if (i < NN) e[i] = (e[i] - mean) * inv;
}

// ---- tiny energy-branch MLP: 1 -> 16 relu -> 8, bf16 out ----
__global__ void k_pe(const float* __restrict__ e, const float* __restrict__ w1,
                     const float* __restrict__ b1, const float* __restrict__ w2,
                     const float* __restrict__ b2, unsigned short* __restrict__ pe, int M) {
    int i = blockIdx.x * blockDim.x + threadIdx.x;
    if (i >= M) return;
    float ev = e[i];
    float h[16];
    #pragma unroll
    for (int j = 0; j < 16; ++j) h[j] = fmaxf(ev * w1[j] + b1[j], 0.f);
    #pragma unroll
    for (int k = 0; k < 8; ++k) {
        float s = b2[k];
        #pragma unroll
        for (int j = 0; j < 16; ++j) s += h[j] * w2[j * 8 + k];
        pe[(size_t)i * 8 + k] = f2b(s);
    }
}

__global__ void k_dis(const float* __restrict__ deg, float* __restrict__ dis) {
    int i = blockIdx.x * blockDim.x + threadIdx.x;
    if (i < NN) dis[i] = 1.0f / sqrtf(deg[i] + 1.0f);
}

// ---- CSR build: block-wise exclusive scan of degrees ----
__global__ void k_scan_block(const float* __restrict__ deg, int* __restrict__ offs,
                             int* __restrict__ bsum) {
    __shared__ int s[256];
    int t = threadIdx.x;
    int base = blockIdx.x * 1024 + t * 4;
    int v0 = (base + 0 < NN) ? (int)deg[base + 0] : 0;
    int v1 = (base + 1 < NN) ? (int)deg[base + 1] : 0;
    int v2 = (base + 2 < NN) ? (int)deg[base + 2] : 0;
    int v3 = (base + 3 < NN) ? (int)deg[base + 3] : 0;
    int lsum = v0 + v1 + v2 + v3;
    s[t] = lsum;
    __syncthreads();
    for (int off = 1; off < 256; off <<= 1) {
        int x = (t >= off) ? s[t - off] : 0;
        __syncthreads();
        s[t] += x;
        __syncthreads();
    }
    if (t == 255) bsum[blockIdx.x] = s[255];
    int run = s[t] - lsum;
    if (base + 0 < NN) offs[base + 0] = run; run += v0;
    if (base + 1 < NN) offs[base + 1] = run; run += v1;
    if (base + 2 < NN) offs[base + 2] = run; run += v2;
    if (base + 3 < NN) offs[base + 3] = run;
}
__global__ void k_scan_tops(int* __restrict__ bsum, int nb) {
    if (blockIdx.x == 0 && threadIdx.x == 0) {
        int acc = 0;
        for (int i = 0; i < nb; ++i) { int t = bsum[i]; bsum[i] = acc; acc += t; }
    }
}
__global__ void k_scan_add(int* __restrict__ offs, const int* __restrict__ bsum) {
    int i = blockIdx.x * blockDim.x + threadIdx.x;
    if (i < NN) offs[i] += bsum[i >> 10];
}
__global__ void k_scatter(const int* __restrict__ row, const int* __restrict__ col,
                          const float* __restrict__ dis, const int* __restrict__ offs,
                          int* __restrict__ cnt, int* __restrict__ crows,
                          float* __restrict__ cnrm) {
    int e = blockIdx.x * blockDim.x + threadIdx.x;
    if (e >= EE) return;
    int c = col[e], r = row[e];
    int p = offs[c] + atomicAdd(&cnt[c], 1);
    crows[p] = r;
    cnrm[p] = dis[r] * dis[c];
}

// ---- GCN aggregation: one wave per node, register accumulation (no atomics) ----
__global__ void k_gagg(const int* __restrict__ offs, const float* __restrict__ degv,
                       const int* __restrict__ crows, const float* __restrict__ cnrm,
                       const float* __restrict__ h, const float* __restrict__ dis,
                       const float* __restrict__ gcn_b, float* __restrict__ g) {
    int wid = (int)((blockIdx.x * (size_t)blockDim.x + threadIdx.x) >> 6);
    int lane = threadIdx.x & 63;
    if (wid >= NN) return;
    int s = offs[wid], eN = s + (int)degv[wid];
    float a0 = 0.f, a1 = 0.f;
    for (int ei = s; ei < eN; ++ei) {
        int r = crows[ei];
        float nr = cnrm[ei];
        const float* hr = h + (size_t)r * CC;
        a0 += nr * hr[lane];
        a1 += nr * hr[lane + 64];
    }
    float dd = dis[wid] * dis[wid];
    const float* hs = h + (size_t)wid * CC;
    g[(size_t)wid * CC + lane]      = gcn_b[lane]      + dd * hs[lane]       + a0;
    g[(size_t)wid * CC + 64 + lane] = gcn_b[64 + lane] + dd * hs[lane + 64] + a1;
}

// ---- f32 weight -> padded bf16 copy ----
__global__ void k_w2b(const float* __restrict__ src, unsigned short* __restrict__ dst,
                      int K, int N, int ldb) {
    int i = blockIdx.x * blockDim.x + threadIdx.x;
    if (i >= K * ldb) return;
    int k = i / ldb, n = i - k * ldb;
    dst[i] = (n < N) ? f2b(src[(size_t)k * N + n]) : (unsigned short)0;
}

// ---- bf16 MFMA GEMM: C = act(A[MxK] @ B[KxN] + bias), A f32 or bf16, C f32 or bf16 ----
// 128x128 tile, 4 waves each computing 64x64 via 4x4 16x16x32 fragments.
__global__ __launch_bounds__(256) void k_mgemm(
    const void* __restrict__ Ap, const int aF32, const int lda,
    const unsigned short* __restrict__ B, const int ldb,
    const float* __restrict__ bias, void* __restrict__ Cp,
    const int outBf16, const int M, const int K, const int N, const int act)
{
    __shared__ unsigned short As[128][40];   // row-major, pad 40 for 16B rows
    __shared__ unsigned short Bs[128][40];   // TRANSPOSED: Bs[n][k]
    int t = threadIdx.x;
    int lane = t & 63, wv = t >> 6;
    int wm = wv >> 1, wn = wv & 1;
    int rowBase = blockIdx.y * 128, colBase = blockIdx.x * 128;
    const float* Af = (const float*)Ap;
    const unsigned short* Ah = (const unsigned short*)Ap;
    f32x4 acc[4][4] = {};
    int kg = lane >> 4, rc = lane & 15;

    for (int kk = 0; kk < K; kk += 32) {
        // stage A: 512 vectors of 8 bf16
        #pragma unroll
        for (int vi = 0; vi < 2; ++vi) {
            int v = t + vi * 256;
            int r = v >> 2, c8 = (v & 3) * 8;
            int gr = rowBase + r, gk = kk + c8;
            unsigned short tmp[8];
            if (gr < M && gk + 8 <= K) {
                if (aF32) {
                    const float* p = Af + (size_t)gr * lda + gk;
                    float4 fa = *(const float4*)p;
                    float4 fb = *(const float4*)(p + 4);
                    tmp[0] = f2b(fa.x); tmp[1] = f2b(fa.y); tmp[2] = f2b(fa.z); tmp[3] = f2b(fa.w);
                    tmp[4] = f2b(fb.x); tmp[5] = f2b(fb.y); tmp[6] = f2b(fb.z); tmp[7] = f2b(fb.w);
                } else {
                    *(short8*)tmp = *(const short8*)(Ah + (size_t)gr * lda + gk);
                }
            } else {
                #pragma unroll
                for (int j = 0; j < 8; ++j) {
                    int k2 = gk + j;
                    unsigned short hv = 0;
                    if (gr < M && k2 < K)
                        hv = aF32 ? f2b(Af[(size_t)gr * lda + k2]) : Ah[(size_t)gr * lda + k2];
                    tmp[j] = hv;
                }
            }
            *(short8*)&As[r][c8] = *(short8*)tmp;
        }
        // stage B transposed: read 8 consecutive n at fixed k, scatter to Bs[n][k]
        #pragma unroll
        for (int vi = 0; vi < 2; ++vi) {
            int v = t + vi * 256;
            int k = v >> 4, n8 = (v & 15) * 8;
            int gk = kk + k, gn = colBase + n8;
            unsigned short tmp[8];
            if (gk < K && gn + 8 <= N) {
                *(short8*)tmp = *(const short8*)(B + (size_t)gk * ldb + gn);
            } else {
                #pragma unroll
                for (int j = 0; j < 8; ++j)
                    tmp[j] = (gk < K && gn + j < N) ? B[(size_t)gk * ldb + gn + j]
                                                    : (unsigned short)0;
            }
            #pragma unroll
            for (int j = 0; j < 8; ++j) Bs[n8 + j][k] = tmp[j];
        }
        __syncthreads();
        short8 afr[4], bfr[4];
        #pragma unroll
        for (int i = 0; i < 4; ++i) {
            afr[i] = *(const short8*)&As[wm * 64 + i * 16 + rc][kg * 8];
            bfr[i] = *(const short8*)&Bs[wn * 64 + i * 16 + rc][kg * 8];
        }
        #pragma unroll
        for (int i = 0; i < 4; ++i)
            #pragma unroll
            for (int j = 0; j < 4; ++j)
                acc[i][j] = __builtin_amdgcn_mfma_f32_16x16x32_bf16(afr[i], bfr[j], acc[i][j], 0, 0, 0);
        __syncthreads();
    }

    float* Cf = (float*)Cp;
    unsigned short* Ch = (unsigned short*)Cp;
    #pragma unroll
    for (int j = 0; j < 4; ++j) {
        int gc = colBase + wn * 64 + j * 16 + rc;
        if (gc >= N) continue;
        float bv = bias ? bias[gc] : 0.f;
        #pragma unroll
        for (int i = 0; i < 4; ++i) {
            #pragma unroll
            for (int q = 0; q < 4; ++q) {
                int gr = rowBase + wm * 64 + i * 16 + kg * 4 + q;
                if (gr >= M) continue;
                float vv = acc[i][j][q] + bv;
                if (act) vv = fmaxf(vv, 0.f);
                if (outBf16) Ch[(size_t)gr * N + gc] = f2b(vv);
                else         Cf[(size_t)gr * N + gc] = vv;
            }
        }
    }
}

// ---- attention fusion: f32 in, bf16 fused out (stride NFP) ----
__global__ void k_fuse(const float* __restrict__ xt, const float* __restrict__ lt,
                       const float* __restrict__ et, const float* __restrict__ aw,
                       const float* __restrict__ ab, unsigned short* __restrict__ fo, int M) {
    int wid = (int)((blockIdx.x * blockDim.x + threadIdx.x) >> 6);
    int lane = threadIdx.x & 63;
    if (wid >= M) return;
    size_t base = (size_t)wid * NFD;
    float xv[4], lv[4], ev[4];
    float dx = 0.f, dl = 0.f, de = 0.f;
    #pragma unroll
    for (int q = 0; q < 4; ++q) {
        int j = q * 64 + lane;
        bool ok = j < NFD;
        float awv = ok ? aw[j] : 0.f;
        xv[q] = ok ? xt[base + j] : 0.f;
        lv[q] = ok ? lt[base + j] : 0.f;
        ev[q] = ok ? et[base + j] : 0.f;
        dx += xv[q] * awv; dl += lv[q] * awv; de += ev[q] * awv;
    }
    dx = wave_sum(dx); dl = wave_sum(dl); de = wave_sum(de);
    float abv = ab[0];
    float sx = 1.f / (1.f + expf(-(dx + abv)));
    float sl = 1.f / (1.f + expf(-(dl + abv)));
    float se = 1.f / (1.f + expf(-(de + abv)));
    float inv = 1.f / (sx + sl + se);
    #pragma unroll
    for (int q = 0; q < 4; ++q) {
        int j = q * 64 + lane;
        if (j < NFD) fo[(size_t)wid * NFP + j] = f2b((sx * xv[q] + sl * lv[q] + se * ev[q]) * inv);
    }
}

__global__ void k_pred(const float* __restrict__ h2, const float* __restrict__ w3,
                       const float* __restrict__ b3, float* __restrict__ pred, int M) {
    int wid = (int)((blockIdx.x * blockDim.x + threadIdx.x) >> 6);
    int lane = threadIdx.x & 63;
    if (wid >= M) return;
    const float* r = h2 + (size_t)wid * CC;
    float s = r[lane] * w3[lane] + r[lane + 64] * w3[lane + 64];
    s = wave_sum(s);
    if (lane == 0) pred[wid] = 1.f / (1.f + expf(-(s + b3[0])));
}

__global__ void k_gather(const float* __restrict__ pred, const int* __restrict__ mask,
                         float* __restrict__ out, int n) {
    int i = blockIdx.x * blockDim.x + threadIdx.x;
    if (i < n) out[i] = pred[mask[i]];
}

static inline void mgemm(const void* A, int aF32, int lda, const unsigned short* B, int ldb,
                         const float* bias, void* C, int outBf16,
                         int M, int K, int N, int act, hipStream_t s) {
    dim3 grid((N + 127) / 128, (M + 127) / 128);
    k_mgemm<<<grid, 256, 0, s>>>(A, aF32, lda, B, ldb, bias, C, outBf16, M, K, N, act);
}

extern "C" void kernel_launch(void* const* d_in, const int* in_sizes, int n_in,
                              void* d_out, int out_size, void* d_ws, size_t ws_size,
                              hipStream_t stream) {
    const float* logits = (const float*)d_in[0];
    const float* x      = (const float*)d_in[1];
    const int*   eidx   = (const int*)d_in[2];
    const int*   mask   = (const int*)d_in[3];
    const float* fp_w1 = (const float*)d_in[4];
    const float* fp_b1 = (const float*)d_in[5];
    const float* fp_w2 = (const float*)d_in[6];
    const float* fp_b2 = (const float*)d_in[7];
    const float* ep_w1 = (const float*)d_in[8];
    const float* ep_b1 = (const float*)d_in[9];
    const float* ep_w2 = (const float*)d_in[10];
    const float* ep_b2 = (const float*)d_in[11];
    const float* lp_w1 = (const float*)d_in[12];
    const float* lp_b1 = (const float*)d_in[13];
    const float* lp_w2 = (const float*)d_in[14];
    const float* lp_b2 = (const float*)d_in[15];
    const float* gcn_w = (const float*)d_in[16];
    const float* gcn_b = (const float*)d_in[17];
    const float* gt_w  = (const float*)d_in[18];
    const float* gt_b  = (const float*)d_in[19];
    const float* af_xw = (const float*)d_in[20];
    const float* af_xb = (const float*)d_in[21];
    const float* af_lw = (const float*)d_in[22];
    const float* af_lb = (const float*)d_in[23];
    const float* af_ew = (const float*)d_in[24];
    const float* af_eb = (const float*)d_in[25];
    const float* af_aw = (const float*)d_in[26];
    const float* af_ab = (const float*)d_in[27];
    const float* fu_w1 = (const float*)d_in[28];
    const float* fu_b1 = (const float*)d_in[29];
    const float* fu_w2 = (const float*)d_in[30];
    const float* fu_b2 = (const float*)d_in[31];
    const float* fu_w3 = (const float*)d_in[32];
    const float* fu_b3 = (const float*)d_in[33];
    const int* row = eidx;
    const int* col = eidx + EE;
    float* out = (float*)d_out;

    // ---- fixed workspace (~119 MB) ----
    char* wsb = (char*)d_ws;
    size_t o = 0;
    auto alloc = [&](size_t bytes) { char* p = wsb + o; o += (bytes + 255) & ~(size_t)255; return p; };
    float* e_   = (float*)alloc((size_t)NN * 4);
    float* degv = (float*)alloc((size_t)NN * 4);
    float* agg  = (float*)alloc((size_t)NN * 4);   // BP agg; later pred
    float* dis  = (float*)alloc((size_t)NN * 4);
    float* scal = (float*)alloc(64);
    int*   offs = (int*)alloc((size_t)(NN + 4) * 4);
    int*   cnt  = (int*)alloc((size_t)NN * 4);
    int*   bsum = (int*)alloc(512);
    int*   crows= (int*)alloc((size_t)EE * 4);
    float* cnrm = (float*)alloc((size_t)EE * 4);
    float* h    = (float*)alloc((size_t)NN * CC * 4);
    float* g    = (float*)alloc((size_t)NN * CC * 4);
    unsigned short* wfp1 = (unsigned short*)alloc((size_t)256 * 512 * 2);
    unsigned short* wfp2 = (unsigned short*)alloc((size_t)512 * 256 * 2);
    unsigned short* wlp1 = (unsigned short*)alloc((size_t)128 * 128 * 2);
    unsigned short* wlp2 = (unsigned short*)alloc((size_t)128 * 64 * 2);
    unsigned short* wgcn = (unsigned short*)alloc((size_t)256 * 128 * 2);
    unsigned short* wgt  = (unsigned short*)alloc((size_t)128 * 256 * 2);
    unsigned short* wafx = (unsigned short*)alloc((size_t)256 * NFP * 2);
    unsigned short* wafl = (unsigned short*)alloc((size_t)64 * NFP * 2);
    unsigned short* wafe = (unsigned short*)alloc((size_t)8 * NFP * 2);
    unsigned short* wfu1 = (unsigned short*)alloc((size_t)NFD * 256 * 2);
    unsigned short* wfu2 = (unsigned short*)alloc((size_t)256 * 128 * 2);
    size_t fixed = o;

    // ---- chunk area: 4688 B/row (Phase B layout; Phase A needs 1536 and aliases it) ----
    const size_t SROW = 4688;
    size_t rem = (ws_size > fixed) ? ws_size - fixed : 0;
    size_t chq = rem / SROW;
    int CH = (chq >= (size_t)NN) ? NN : (int)chq;
    if (CH < 1) CH = 1;
    char* cb = wsb + fixed;
    int nch = (NN + CH - 1) / CH;

    hipMemsetAsync(degv, 0, (size_t)NN * 4, stream);
    hipMemsetAsync(scal, 0, 64, stream);
    hipMemsetAsync(cnt,  0, (size_t)NN * 4, stream);

    // ---- energy + BP + standardize ----
    k_energy<<<(NN + 3) / 4, 256, 0, stream>>>(logits, e_);
    k_deg<<<(EE + 255) / 256, 256, 0, stream>>>(col, degv);
    for (int it = 0; it < 2; ++it) {
        hipMemsetAsync(agg, 0, (size_t)NN * 4, stream);
        k_prop<<<(EE + 255) / 256, 256, 0, stream>>>(row, col, e_, degv, agg);
        k_combine<<<(NN + 255) / 256, 256, 0, stream>>>(e_, agg);
    }
    k_reduce<<<256, 256, 0, stream>>>(e_, &scal[0], nullptr);
    k_reduce<<<256, 256, 0, stream>>>(e_, &scal[1], &scal[0]);
    k_standardize<<<(NN + 255) / 256, 256, 0, stream>>>(e_, scal);
    k_dis<<<(NN + 255) / 256, 256, 0, stream>>>(degv, dis);

    // ---- CSR build ----
    int nb = (NN + 1023) / 1024;
    k_scan_block<<<nb, 256, 0, stream>>>(degv, offs, bsum);
    k_scan_tops<<<1, 64, 0, stream>>>(bsum, nb);
    k_scan_add<<<(NN + 255) / 256, 256, 0, stream>>>(offs, bsum);
    k_scatter<<<(EE + 255) / 256, 256, 0, stream>>>(row, col, dis, offs, cnt, crows, cnrm);

    // ---- weights -> bf16 ----
    auto w2b = [&](const float* s, unsigned short* d, int K, int N, int ldb) {
        int tot = K * ldb;
        k_w2b<<<(tot + 255) / 256, 256, 0, stream>>>(s, d, K, N, ldb);
    };
    w2b(fp_w1, wfp1, 256, 512, 512);
    w2b(fp_w2, wfp2, 512, 256, 256);
    w2b(lp_w1, wlp1, 128, 128, 128);
    w2b(lp_w2, wlp2, 128, 64, 64);
    w2b(gcn_w, wgcn, 256, 128, 128);
    w2b(gt_w,  wgt,  128, 256, 256);
    w2b(af_xw, wafx, 256, NFD, NFP);
    w2b(af_lw, wafl, 64,  NFD, NFP);
    w2b(af_ew, wafe, 8,   NFD, NFP);
    w2b(fu_w1, wfu1, NFD, 256, 256);
    w2b(fu_w2, wfu2, 256, 128, 128);

    // ---- Phase A (chunked): x -> hid -> px -> h ----
    for (int c = 0; c < nch; ++c) {
        int base = c * CH;
        int m = (NN - base < CH) ? (NN - base) : CH;
        unsigned short* hid = (unsigned short*)cb;                       // 1024B/row
        unsigned short* px  = (unsigned short*)(cb + (size_t)1024 * CH); // 512B/row
        mgemm(x + (size_t)base * FF, 1, 256, wfp1, 512, fp_b1, hid, 1, m, 256, 512, 1, stream);
        mgemm(hid, 0, 512, wfp2, 256, fp_b2, px, 1, m, 512, 256, 0, stream);
        mgemm(px, 0, 256, wgcn, 128, nullptr, h + (size_t)base * CC, 0, m, 256, 128, 0, stream);
    }

    // ---- GCN aggregation (gather, no atomics) ----
    k_gagg<<<(int)(((size_t)NN * 64 + 255) / 256), 256, 0, stream>>>(
        offs, degv, crows, cnrm, h, dis, gcn_b, g);

    // ---- Phase B (chunked) ----
    for (int c = 0; c < nch; ++c) {
        int base = c * CH;
        int m = (NN - base < CH) ? (NN - base) : CH;
        unsigned short* lph = (unsigned short*)cb;                         // 256B/row
        unsigned short* pl  = (unsigned short*)(cb + (size_t)256 * CH);    // 128
        unsigned short* peb = (unsigned short*)(cb + (size_t)384 * CH);    // 16
        unsigned short* gx  = (unsigned short*)(cb + (size_t)400 * CH);    // 512
        float* xt  = (float*)(cb + (size_t)912 * CH);                      // 784
        float* lt  = (float*)(cb + (size_t)1696 * CH);                     // 784
        float* et  = (float*)(cb + (size_t)2480 * CH);                     // 784
        unsigned short* fus = (unsigned short*)(cb + (size_t)3264 * CH);   // 400 (stride NFP)
        unsigned short* h1  = (unsigned short*)(cb + (size_t)3664 * CH);   // 512
        float* h2  = (float*)(cb + (size_t)4176 * CH);                     // 512

        mgemm(logits + (size_t)base * CC, 1, 128, wlp1, 128, lp_b1, lph, 1, m, 128, 128, 1, stream);
        mgemm(lph, 0, 128, wlp2, 64, lp_b2, pl, 1, m, 128, 64, 0, stream);
        k_pe<<<(m + 255) / 256, 256, 0, stream>>>(e_ + base, ep_w1, ep_b1, ep_w2, ep_b2, peb, m);

        mgemm(g + (size_t)base * CC, 1, 128, wgt, 256, gt_b, gx, 1, m, 128, 256, 0, stream);
        mgemm(gx, 0, 256, wafx, NFP, af_xb, xt, 0, m, 256, NFD, 0, stream);
        mgemm(pl, 0, 64, wafl, NFP, af_lb, lt, 0, m, 64, NFD, 0, stream);
        mgemm(peb, 0, 8, wafe, NFP, af_eb, et, 0, m, 8, NFD, 0, stream);
        k_fuse<<<(m + 3) / 4, 256, 0, stream>>>(xt, lt, et, af_aw, af_ab, fus, m);

        mgemm(fus, 0, NFP, wfu1, 256, fu_b1, h1, 1, m, NFD, 256, 1, stream);
        mgemm(h1, 0, 256, wfu2, 128, fu_b2, h2, 0, m, 256, 128, 1, stream);
        k_pred<<<(m + 3) / 4, 256, 0, stream>>>(h2, fu_w3, fu_b3, agg + base, m);
    }

    k_gather<<<(out_size + 255) / 256, 256, 0, stream>>>(agg, mask, out, out_size);
}

// Round 9
// 1677.754 us; speedup vs baseline: 3.1667x; 1.1417x over previous
//
#include <hip/hip_runtime.h>
#include <math.h>

#define NN 100000
#define EE 1600000
#define FF 256
#define CC 128
#define NFD 193
#define NFP 200   // padded stride for fus (keeps bf16 A-reads 16B-aligned)

typedef __attribute__((ext_vector_type(8))) short short8;
typedef __attribute__((ext_vector_type(4))) float f32x4;

__device__ __forceinline__ unsigned short f2b(float f) {
    unsigned u = __float_as_uint(f);
    u += 0x7FFF + ((u >> 16) & 1);   // round-to-nearest-even
    return (unsigned short)(u >> 16);
}
__device__ __forceinline__ float b2f_lo(unsigned u) { return __uint_as_float(u << 16); }
__device__ __forceinline__ float b2f_hi(unsigned u) { return __uint_as_float(u & 0xffff0000u); }

__device__ __forceinline__ float wave_sum(float v) {
    #pragma unroll
    for (int o = 32; o > 0; o >>= 1) v += __shfl_xor(v, o, 64);
    return v;
}
__device__ __forceinline__ float wave_max(float v) {
    #pragma unroll
    for (int o = 32; o > 0; o >>= 1) v = fmaxf(v, __shfl_xor(v, o, 64));
    return v;
}

// ---- energy = logsumexp over C=128, one wave per row ----
__global__ void k_energy(const float* __restrict__ logits, float* __restrict__ e) {
    int wid = (int)((blockIdx.x * blockDim.x + threadIdx.x) >> 6);
    int lane = threadIdx.x & 63;
    if (wid >= NN) return;
    const float* rowp = logits + (size_t)wid * CC;
    float a = rowp[lane], b = rowp[lane + 64];
    float m = wave_max(fmaxf(a, b));
    float s = expf(a - m) + expf(b - m);
    s = wave_sum(s);
    if (lane == 0) e[wid] = m + logf(s);
}

__global__ void k_deg(const int* __restrict__ col, float* __restrict__ deg) {
    int i = blockIdx.x * blockDim.x + threadIdx.x;
    if (i < EE) atomicAdd(&deg[col[i]], 1.0f);
}

__global__ void k_prop(const int* __restrict__ row, const int* __restrict__ col,
                       const float* __restrict__ e, const float* __restrict__ deg,
                       float* __restrict__ agg) {
    int i = blockIdx.x * blockDim.x + threadIdx.x;
    if (i >= EE) return;
    int c = col[i];
    float d = deg[c];
    if (d > 0.f) atomicAdd(&agg[c], e[row[i]] / d);
}

__global__ void k_combine(float* __restrict__ e, const float* __restrict__ agg) {
    int i = blockIdx.x * blockDim.x + threadIdx.x;
    if (i < NN) e[i] = 0.5f * e[i] + 0.5f * agg[i];
}

__global__ void k_reduce(const float* __restrict__ e, float* __restrict__ out,
                         const float* __restrict__ meanptr) {
    float mean = meanptr ? (*meanptr) / (float)NN : 0.0f;
    float s = 0.f;
    for (int i = blockIdx.x * blockDim.x + threadIdx.x; i < NN; i += gridDim.x * blockDim.x) {
        if (meanptr) { float v = e[i] - mean; s += v * v; }
        else s += e[i];
    }
    s = wave_sum(s);
    __shared__ float ls[4];
    int lane = threadIdx.x & 63, w = threadIdx.x >> 6;
    if (lane == 0) ls[w] = s;
    __syncthreads();
    if (threadIdx.x == 0) atomicAdd(out, ls[0] + ls[1] + ls[2] + ls[3]);
}

__global__ void k_standardize(float* __restrict__ e, const float* __restrict__ scal) {
    float mean = scal[0] / (float)NN;
    float var = scal[1] / (float)(NN - 1);
    float inv = 1.0f / (sqrtf(var) + 1e-6f);
    int i = blockIdx.x * blockDim.x + threadIdx.x;
    if (i < NN) e[i] = (e[i] - mean) * inv;
}

// ---- tiny energy-branch MLP: 1 -> 16 relu -> 8, bf16 out ----
__global__ void k_pe(const float* __restrict__ e, const float* __restrict__ w1,
                     const float* __restrict__ b1, const float* __restrict__ w2,
                     const float* __restrict__ b2, unsigned short* __restrict__ pe, int M) {
    int i = blockIdx.x * blockDim.x + threadIdx.x;
    if (i >= M) return;
    float ev = e[i];
    float h[16];
    #pragma unroll
    for (int j = 0; j < 16; ++j) h[j] = fmaxf(ev * w1[j] + b1[j], 0.f);
    #pragma unroll
    for (int k = 0; k < 8; ++k) {
        float s = b2[k];
        #pragma unroll
        for (int j = 0; j < 16; ++j) s += h[j] * w2[j * 8 + k];
        pe[(size_t)i * 8 + k] = f2b(s);
    }
}

__global__ void k_dis(const float* __restrict__ deg, float* __restrict__ dis) {
    int i = blockIdx.x * blockDim.x + threadIdx.x;
    if (i < NN) dis[i] = 1.0f / sqrtf(deg[i] + 1.0f);
}

// ---- CSR build: block-wise exclusive scan of degrees ----
__global__ void k_scan_block(const float* __restrict__ deg, int* __restrict__ offs,
                             int* __restrict__ bsum) {
    __shared__ int s[256];
    int t = threadIdx.x;
    int base = blockIdx.x * 1024 + t * 4;
    int v0 = (base + 0 < NN) ? (int)deg[base + 0] : 0;
    int v1 = (base + 1 < NN) ? (int)deg[base + 1] : 0;
    int v2 = (base + 2 < NN) ? (int)deg[base + 2] : 0;
    int v3 = (base + 3 < NN) ? (int)deg[base + 3] : 0;
    int lsum = v0 + v1 + v2 + v3;
    s[t] = lsum;
    __syncthreads();
    for (int off = 1; off < 256; off <<= 1) {
        int x = (t >= off) ? s[t - off] : 0;
        __syncthreads();
        s[t] += x;
        __syncthreads();
    }
    if (t == 255) bsum[blockIdx.x] = s[255];
    int run = s[t] - lsum;
    if (base + 0 < NN) offs[base + 0] = run; run += v0;
    if (base + 1 < NN) offs[base + 1] = run; run += v1;
    if (base + 2 < NN) offs[base + 2] = run; run += v2;
    if (base + 3 < NN) offs[base + 3] = run;
}
__global__ void k_scan_tops(int* __restrict__ bsum, int nb) {
    if (blockIdx.x == 0 && threadIdx.x == 0) {
        int acc = 0;
        for (int i = 0; i < nb; ++i) { int t = bsum[i]; bsum[i] = acc; acc += t; }
    }
}
__global__ void k_scan_add(int* __restrict__ offs, const int* __restrict__ bsum) {
    int i = blockIdx.x * blockDim.x + threadIdx.x;
    if (i < NN) offs[i] += bsum[i >> 10];
}
__global__ void k_scatter(const int* __restrict__ row, const int* __restrict__ col,
                          const float* __restrict__ dis, const int* __restrict__ offs,
                          int* __restrict__ cnt, int* __restrict__ crows,
                          float* __restrict__ cnrm) {
    int e = blockIdx.x * blockDim.x + threadIdx.x;
    if (e >= EE) return;
    int c = col[e], r = row[e];
    int p = offs[c] + atomicAdd(&cnt[c], 1);
    crows[p] = r;
    cnrm[p] = dis[r] * dis[c];
}

// ---- GCN aggregation: one wave per node, bf16 h, register accumulation ----
// lane owns channels (2*lane, 2*lane+1): one dword per h-row per lane.
__global__ void k_gagg(const int* __restrict__ offs, const float* __restrict__ degv,
                       const int* __restrict__ crows, const float* __restrict__ cnrm,
                       const unsigned short* __restrict__ hb, const float* __restrict__ dis,
                       const float* __restrict__ gcn_b, float* __restrict__ g) {
    int wid = (int)((blockIdx.x * (size_t)blockDim.x + threadIdx.x) >> 6);
    int lane = threadIdx.x & 63;
    if (wid >= NN) return;
    int s = offs[wid], eN = s + (int)degv[wid];
    float a0 = 0.f, a1 = 0.f;
    for (int ei = s; ei < eN; ++ei) {
        int r = crows[ei];
        float nr = cnrm[ei];
        unsigned pv = *(const unsigned*)(hb + (size_t)r * CC + 2 * lane);
        a0 += nr * b2f_lo(pv);
        a1 += nr * b2f_hi(pv);
    }
    float dd = dis[wid] * dis[wid];
    unsigned sv = *(const unsigned*)(hb + (size_t)wid * CC + 2 * lane);
    float g0 = gcn_b[2 * lane]     + dd * b2f_lo(sv) + a0;
    float g1 = gcn_b[2 * lane + 1] + dd * b2f_hi(sv) + a1;
    *(float2*)(g + (size_t)wid * CC + 2 * lane) = make_float2(g0, g1);
}

// ---- f32 weight [K][N] -> bf16 TRANSPOSED [N][KP], zero-padded k>=K ----
__global__ void k_w2bt(const float* __restrict__ src, unsigned short* __restrict__ dst,
                       int K, int N, int KP) {
    int i = blockIdx.x * blockDim.x + threadIdx.x;
    if (i >= N * KP) return;
    int n = i / KP, k = i - n * KP;
    dst[i] = (k < K) ? f2b(src[(size_t)k * N + n]) : (unsigned short)0;
}

// ---- bf16 MFMA GEMM: C = act(A[MxK] @ W[KxN] + bias), W given TRANSPOSED [N][KP] ----
// 128x128 tile, 4 waves each computing 64x64 via 4x4 16x16x32 fragments.
// Both A and B staged with conflict-free b128 LDS writes.
__global__ __launch_bounds__(256) void k_mgemm(
    const void* __restrict__ Ap, const int aF32, const int lda,
    const unsigned short* __restrict__ BT, const int ldbt,
    const float* __restrict__ bias, void* __restrict__ Cp,
    const int outBf16, const int M, const int K, const int N, const int act)
{
    __shared__ unsigned short As[128][40];   // row-major [m][k], pad 40 for 16B rows
    __shared__ unsigned short Bs[128][40];   // row-major [n][k], pad 40
    int t = threadIdx.x;
    int lane = t & 63, wv = t >> 6;
    int wm = wv >> 1, wn = wv & 1;
    int rowBase = blockIdx.y * 128, colBase = blockIdx.x * 128;
    const float* Af = (const float*)Ap;
    const unsigned short* Ah = (const unsigned short*)Ap;
    f32x4 acc[4][4] = {};
    int kg = lane >> 4, rc = lane & 15;

    for (int kk = 0; kk < K; kk += 32) {
        // stage A: 512 vectors of 8 bf16 (b128 writes, conflict-free)
        #pragma unroll
        for (int vi = 0; vi < 2; ++vi) {
            int v = t + vi * 256;
            int r = v >> 2, c8 = (v & 3) * 8;
            int gr = rowBase + r, gk = kk + c8;
            unsigned short tmp[8];
            if (gr < M && gk + 8 <= K) {
                if (aF32) {
                    const float* p = Af + (size_t)gr * lda + gk;
                    float4 fa = *(const float4*)p;
                    float4 fb = *(const float4*)(p + 4);
                    tmp[0] = f2b(fa.x); tmp[1] = f2b(fa.y); tmp[2] = f2b(fa.z); tmp[3] = f2b(fa.w);
                    tmp[4] = f2b(fb.x); tmp[5] = f2b(fb.y); tmp[6] = f2b(fb.z); tmp[7] = f2b(fb.w);
                } else {
                    *(short8*)tmp = *(const short8*)(Ah + (size_t)gr * lda + gk);
                }
            } else {
                #pragma unroll
                for (int j = 0; j < 8; ++j) {
                    int k2 = gk + j;
                    unsigned short hv = 0;
                    if (gr < M && k2 < K)
                        hv = aF32 ? f2b(Af[(size_t)gr * lda + k2]) : Ah[(size_t)gr * lda + k2];
                    tmp[j] = hv;
                }
            }
            *(short8*)&As[r][c8] = *(short8*)tmp;
        }
        // stage B from transposed weights: identical pattern to A (b128, conflict-free)
        // KP padding guarantees gk+8 <= ldbt always in-bounds; zero rows for gn >= N.
        #pragma unroll
        for (int vi = 0; vi < 2; ++vi) {
            int v = t + vi * 256;
            int r = v >> 2, c8 = (v & 3) * 8;
            int gn = colBase + r, gk = kk + c8;
            unsigned short tmp[8];
            if (gn < N) {
                *(short8*)tmp = *(const short8*)(BT + (size_t)gn * ldbt + gk);
            } else {
                #pragma unroll
                for (int j = 0; j < 8; ++j) tmp[j] = 0;
            }
            *(short8*)&Bs[r][c8] = *(short8*)tmp;
        }
        __syncthreads();
        short8 afr[4], bfr[4];
        #pragma unroll
        for (int i = 0; i < 4; ++i) {
            afr[i] = *(const short8*)&As[wm * 64 + i * 16 + rc][kg * 8];
            bfr[i] = *(const short8*)&Bs[wn * 64 + i * 16 + rc][kg * 8];
        }
        #pragma unroll
        for (int i = 0; i < 4; ++i)
            #pragma unroll
            for (int j = 0; j < 4; ++j)
                acc[i][j] = __builtin_amdgcn_mfma_f32_16x16x32_bf16(afr[i], bfr[j], acc[i][j], 0, 0, 0);
        __syncthreads();
    }

    float* Cf = (float*)Cp;
    unsigned short* Ch = (unsigned short*)Cp;
    #pragma unroll
    for (int j = 0; j < 4; ++j) {
        int gc = colBase + wn * 64 + j * 16 + rc;
        if (gc >= N) continue;
        float bv = bias ? bias[gc] : 0.f;
        #pragma unroll
        for (int i = 0; i < 4; ++i) {
            #pragma unroll
            for (int q = 0; q < 4; ++q) {
                int gr = rowBase + wm * 64 + i * 16 + kg * 4 + q;
                if (gr >= M) continue;
                float vv = acc[i][j][q] + bv;
                if (act) vv = fmaxf(vv, 0.f);
                if (outBf16) Ch[(size_t)gr * N + gc] = f2b(vv);
                else         Cf[(size_t)gr * N + gc] = vv;
            }
        }
    }
}

// ---- attention fusion: f32 in (stride NFD), bf16 fused out (stride NFP) ----
__global__ void k_fuse(const float* __restrict__ xt, const float* __restrict__ lt,
                       const float* __restrict__ et, const float* __restrict__ aw,
                       const float* __restrict__ ab, unsigned short* __restrict__ fo, int M) {
    int wid = (int)((blockIdx.x * blockDim.x + threadIdx.x) >> 6);
    int lane = threadIdx.x & 63;
    if (wid >= M) return;
    size_t base = (size_t)wid * NFD;
    float xv[4], lv[4], ev[4];
    float dx = 0.f, dl = 0.f, de = 0.f;
    #pragma unroll
    for (int q = 0; q < 4; ++q) {
        int j = q * 64 + lane;
        bool ok = j < NFD;
        float awv = ok ? aw[j] : 0.f;
        xv[q] = ok ? xt[base + j] : 0.f;
        lv[q] = ok ? lt[base + j] : 0.f;
        ev[q] = ok ? et[base + j] : 0.f;
        dx += xv[q] * awv; dl += lv[q] * awv; de += ev[q] * awv;
    }
    dx = wave_sum(dx); dl = wave_sum(dl); de = wave_sum(de);
    float abv = ab[0];
    float sx = 1.f / (1.f + expf(-(dx + abv)));
    float sl = 1.f / (1.f + expf(-(dl + abv)));
    float se = 1.f / (1.f + expf(-(de + abv)));
    float inv = 1.f / (sx + sl + se);
    #pragma unroll
    for (int q = 0; q < 4; ++q) {
        int j = q * 64 + lane;
        if (j < NFD) fo[(size_t)wid * NFP + j] = f2b((sx * xv[q] + sl * lv[q] + se * ev[q]) * inv);
    }
}

__global__ void k_pred(const float* __restrict__ h2, const float* __restrict__ w3,
                       const float* __restrict__ b3, float* __restrict__ pred, int M) {
    int wid = (int)((blockIdx.x * blockDim.x + threadIdx.x) >> 6);
    int lane = threadIdx.x & 63;
    if (wid >= M) return;
    const float* r = h2 + (size_t)wid * CC;
    float s = r[lane] * w3[lane] + r[lane + 64] * w3[lane + 64];
    s = wave_sum(s);
    if (lane == 0) pred[wid] = 1.f / (1.f + expf(-(s + b3[0])));
}

__global__ void k_gather(const float* __restrict__ pred, const int* __restrict__ mask,
                         float* __restrict__ out, int n) {
    int i = blockIdx.x * blockDim.x + threadIdx.x;
    if (i < n) out[i] = pred[mask[i]];
}

static inline void mgemm(const void* A, int aF32, int lda, const unsigned short* BT, int ldbt,
                         const float* bias, void* C, int outBf16,
                         int M, int K, int N, int act, hipStream_t s) {
    dim3 grid((N + 127) / 128, (M + 127) / 128);
    k_mgemm<<<grid, 256, 0, s>>>(A, aF32, lda, BT, ldbt, bias, C, outBf16, M, K, N, act);
}

extern "C" void kernel_launch(void* const* d_in, const int* in_sizes, int n_in,
                              void* d_out, int out_size, void* d_ws, size_t ws_size,
                              hipStream_t stream) {
    const float* logits = (const float*)d_in[0];
    const float* x      = (const float*)d_in[1];
    const int*   eidx   = (const int*)d_in[2];
    const int*   mask   = (const int*)d_in[3];
    const float* fp_w1 = (const float*)d_in[4];
    const float* fp_b1 = (const float*)d_in[5];
    const float* fp_w2 = (const float*)d_in[6];
    const float* fp_b2 = (const float*)d_in[7];
    const float* ep_w1 = (const float*)d_in[8];
    const float* ep_b1 = (const float*)d_in[9];
    const float* ep_w2 = (const float*)d_in[10];
    const float* ep_b2 = (const float*)d_in[11];
    const float* lp_w1 = (const float*)d_in[12];
    const float* lp_b1 = (const float*)d_in[13];
    const float* lp_w2 = (const float*)d_in[14];
    const float* lp_b2 = (const float*)d_in[15];
    const float* gcn_w = (const float*)d_in[16];
    const float* gcn_b = (const float*)d_in[17];
    const float* gt_w  = (const float*)d_in[18];
    const float* gt_b  = (const float*)d_in[19];
    const float* af_xw = (const float*)d_in[20];
    const float* af_xb = (const float*)d_in[21];
    const float* af_lw = (const float*)d_in[22];
    const float* af_lb = (const float*)d_in[23];
    const float* af_ew = (const float*)d_in[24];
    const float* af_eb = (const float*)d_in[25];
    const float* af_aw = (const float*)d_in[26];
    const float* af_ab = (const float*)d_in[27];
    const float* fu_w1 = (const float*)d_in[28];
    const float* fu_b1 = (const float*)d_in[29];
    const float* fu_w2 = (const float*)d_in[30];
    const float* fu_b2 = (const float*)d_in[31];
    const float* fu_w3 = (const float*)d_in[32];
    const float* fu_b3 = (const float*)d_in[33];
    const int* row = eidx;
    const int* col = eidx + EE;
    float* out = (float*)d_out;

    // ---- fixed workspace (~95 MB) ----
    char* wsb = (char*)d_ws;
    size_t o = 0;
    auto alloc = [&](size_t bytes) { char* p = wsb + o; o += (bytes + 255) & ~(size_t)255; return p; };
    float* e_   = (float*)alloc((size_t)NN * 4);
    float* degv = (float*)alloc((size_t)NN * 4);
    float* agg  = (float*)alloc((size_t)NN * 4);   // BP agg; later pred
    float* dis  = (float*)alloc((size_t)NN * 4);
    float* scal = (float*)alloc(64);
    int*   offs = (int*)alloc((size_t)(NN + 4) * 4);
    int*   cnt  = (int*)alloc((size_t)NN * 4);
    int*   bsum = (int*)alloc(512);
    int*   crows= (int*)alloc((size_t)EE * 4);
    float* cnrm = (float*)alloc((size_t)EE * 4);
    unsigned short* hb = (unsigned short*)alloc((size_t)NN * CC * 2);  // bf16 h
    float* g    = (float*)alloc((size_t)NN * CC * 4);
    // transposed bf16 weights [N][KP]
    unsigned short* wfp1T = (unsigned short*)alloc((size_t)512 * 256 * 2);
    unsigned short* wfp2T = (unsigned short*)alloc((size_t)256 * 512 * 2);
    unsigned short* wlp1T = (unsigned short*)alloc((size_t)128 * 128 * 2);
    unsigned short* wlp2T = (unsigned short*)alloc((size_t)64 * 128 * 2);
    unsigned short* wgcnT = (unsigned short*)alloc((size_t)128 * 256 * 2);
    unsigned short* wgtT  = (unsigned short*)alloc((size_t)256 * 128 * 2);
    unsigned short* wafxT = (unsigned short*)alloc((size_t)NFD * 256 * 2);
    unsigned short* waflT = (unsigned short*)alloc((size_t)NFD * 64 * 2);
    unsigned short* wafeT = (unsigned short*)alloc((size_t)NFD * 32 * 2);
    unsigned short* wfu1T = (unsigned short*)alloc((size_t)256 * 224 * 2);
    unsigned short* wfu2T = (unsigned short*)alloc((size_t)128 * 256 * 2);
    size_t fixed = o;

    // ---- chunk area: 4688 B/row (Phase B layout; Phase A needs 1536 and aliases it) ----
    const size_t SROW = 4688;
    size_t rem = (ws_size > fixed) ? ws_size - fixed : 0;
    size_t chq = rem / SROW;
    int CH = (chq >= (size_t)NN) ? NN : (int)chq;
    if (CH < 1) CH = 1;
    char* cb = wsb + fixed;
    int nch = (NN + CH - 1) / CH;

    hipMemsetAsync(degv, 0, (size_t)NN * 4, stream);
    hipMemsetAsync(scal, 0, 64, stream);
    hipMemsetAsync(cnt,  0, (size_t)NN * 4, stream);

    // ---- energy + BP + standardize ----
    k_energy<<<(NN + 3) / 4, 256, 0, stream>>>(logits, e_);
    k_deg<<<(EE + 255) / 256, 256, 0, stream>>>(col, degv);
    for (int it = 0; it < 2; ++it) {
        hipMemsetAsync(agg, 0, (size_t)NN * 4, stream);
        k_prop<<<(EE + 255) / 256, 256, 0, stream>>>(row, col, e_, degv, agg);
        k_combine<<<(NN + 255) / 256, 256, 0, stream>>>(e_, agg);
    }
    k_reduce<<<256, 256, 0, stream>>>(e_, &scal[0], nullptr);
    k_reduce<<<256, 256, 0, stream>>>(e_, &scal[1], &scal[0]);
    k_standardize<<<(NN + 255) / 256, 256, 0, stream>>>(e_, scal);
    k_dis<<<(NN + 255) / 256, 256, 0, stream>>>(degv, dis);

    // ---- CSR build ----
    int nb = (NN + 1023) / 1024;
    k_scan_block<<<nb, 256, 0, stream>>>(degv, offs, bsum);
    k_scan_tops<<<1, 64, 0, stream>>>(bsum, nb);
    k_scan_add<<<(NN + 255) / 256, 256, 0, stream>>>(offs, bsum);
    k_scatter<<<(EE + 255) / 256, 256, 0, stream>>>(row, col, dis, offs, cnt, crows, cnrm);

    // ---- weights -> transposed bf16 [N][KP] ----
    auto w2bt = [&](const float* s, unsigned short* d, int K, int N, int KP) {
        int tot = N * KP;
        k_w2bt<<<(tot + 255) / 256, 256, 0, stream>>>(s, d, K, N, KP);
    };
    w2bt(fp_w1, wfp1T, 256, 512, 256);
    w2bt(fp_w2, wfp2T, 512, 256, 512);
    w2bt(lp_w1, wlp1T, 128, 128, 128);
    w2bt(lp_w2, wlp2T, 128, 64, 128);
    w2bt(gcn_w, wgcnT, 256, 128, 256);
    w2bt(gt_w,  wgtT,  128, 256, 128);
    w2bt(af_xw, wafxT, 256, NFD, 256);
    w2bt(af_lw, waflT, 64,  NFD, 64);
    w2bt(af_ew, wafeT, 8,   NFD, 32);
    w2bt(fu_w1, wfu1T, NFD, 256, 224);
    w2bt(fu_w2, wfu2T, 256, 128, 256);

    // ---- Phase A (chunked): x -> hid -> px -> h(bf16) ----
    for (int c = 0; c < nch; ++c) {
        int base = c * CH;
        int m = (NN - base < CH) ? (NN - base) : CH;
        unsigned short* hid = (unsigned short*)cb;                       // 1024B/row
        unsigned short* px  = (unsigned short*)(cb + (size_t)1024 * CH); // 512B/row
        mgemm(x + (size_t)base * FF, 1, 256, wfp1T, 256, fp_b1, hid, 1, m, 256, 512, 1, stream);
        mgemm(hid, 0, 512, wfp2T, 512, fp_b2, px, 1, m, 512, 256, 0, stream);
        mgemm(px, 0, 256, wgcnT, 256, nullptr, hb + (size_t)base * CC, 1, m, 256, 128, 0, stream);
    }

    // ---- GCN aggregation (gather, no atomics, bf16 h) ----
    k_gagg<<<(int)(((size_t)NN * 64 + 255) / 256), 256, 0, stream>>>(
        offs, degv, crows, cnrm, hb, dis, gcn_b, g);

    // ---- Phase B (chunked) ----
    for (int c = 0; c < nch; ++c) {
        int base = c * CH;
        int m = (NN - base < CH) ? (NN - base) : CH;
        unsigned short* lph = (unsigned short*)cb;                         // 256B/row
        unsigned short* pl  = (unsigned short*)(cb + (size_t)256 * CH);    // 128
        unsigned short* peb = (unsigned short*)(cb + (size_t)384 * CH);    // 16
        unsigned short* gx  = (unsigned short*)(cb + (size_t)400 * CH);    // 512
        float* xt  = (float*)(cb + (size_t)912 * CH);                      // 784
        float* lt  = (float*)(cb + (size_t)1696 * CH);                     // 784
        float* et  = (float*)(cb + (size_t)2480 * CH);                     // 784
        unsigned short* fus = (unsigned short*)(cb + (size_t)3264 * CH);   // 400 (stride NFP)
        unsigned short* h1  = (unsigned short*)(cb + (size_t)3664 * CH);   // 512
        float* h2  = (float*)(cb + (size_t)4176 * CH);                     // 512

        mgemm(logits + (size_t)base * CC, 1, 128, wlp1T, 128, lp_b1, lph, 1, m, 128, 128, 1, stream);
        mgemm(lph, 0, 128, wlp2T, 128, lp_b2, pl, 1, m, 128, 64, 0, stream);
        k_pe<<<(m + 255) / 256, 256, 0, stream>>>(e_ + base, ep_w1, ep_b1, ep_w2, ep_b2, peb, m);

        mgemm(g + (size_t)base * CC, 1, 128, wgtT, 128, gt_b, gx, 1, m, 128, 256, 0, stream);
        mgemm(gx, 0, 256, wafxT, 256, af_xb, xt, 0, m, 256, NFD, 0, stream);
        mgemm(pl, 0, 64, waflT, 64, af_lb, lt, 0, m, 64, NFD, 0, stream);
        mgemm(peb, 0, 8, wafeT, 32, af_eb, et, 0, m, 8, NFD, 0, stream);
        k_fuse<<<(m + 3) / 4, 256, 0, stream>>>(xt, lt, et, af_aw, af_ab, fus, m);

        mgemm(fus, 0, NFP, wfu1T, 224, fu_b1, h1, 1, m, NFD, 256, 1, stream);
        mgemm(h1, 0, 256, wfu2T, 256, fu_b2, h2, 0, m, 256, 128, 1, stream);
        k_pred<<<(m + 3) / 4, 256, 0, stream>>>(h2, fu_w3, fu_b3, agg + base, m);
    }

    k_gather<<<(out_size + 255) / 256, 256, 0, stream>>>(agg, mask, out, out_size);
}

// Round 10
// 1336.831 us; speedup vs baseline: 3.9743x; 1.2550x over previous
//
#include <hip/hip_runtime.h>
#include <math.h>

#define NN 100000
#define EE 1600000
#define FF 256
#define CC 128
#define NFD 193
#define NFP 200   // padded stride for fus (keeps bf16 A-reads 16B-aligned)

typedef __attribute__((ext_vector_type(8))) short short8;
typedef __attribute__((ext_vector_type(4))) float f32x4;

__device__ __forceinline__ unsigned short f2b(float f) {
    unsigned u = __float_as_uint(f);
    u += 0x7FFF + ((u >> 16) & 1);   // round-to-nearest-even
    return (unsigned short)(u >> 16);
}
__device__ __forceinline__ float b2f_lo(unsigned u) { return __uint_as_float(u << 16); }
__device__ __forceinline__ float b2f_hi(unsigned u) { return __uint_as_float(u & 0xffff0000u); }

__device__ __forceinline__ float wave_sum(float v) {
    #pragma unroll
    for (int o = 32; o > 0; o >>= 1) v += __shfl_xor(v, o, 64);
    return v;
}
__device__ __forceinline__ float wave_max(float v) {
    #pragma unroll
    for (int o = 32; o > 0; o >>= 1) v = fmaxf(v, __shfl_xor(v, o, 64));
    return v;
}

// ---- energy = logsumexp over C=128, one wave per row ----
__global__ void k_energy(const float* __restrict__ logits, float* __restrict__ e) {
    int wid = (int)((blockIdx.x * blockDim.x + threadIdx.x) >> 6);
    int lane = threadIdx.x & 63;
    if (wid >= NN) return;
    const float* rowp = logits + (size_t)wid * CC;
    float a = rowp[lane], b = rowp[lane + 64];
    float m = wave_max(fmaxf(a, b));
    float s = expf(a - m) + expf(b - m);
    s = wave_sum(s);
    if (lane == 0) e[wid] = m + logf(s);
}

__global__ void k_deg(const int* __restrict__ col, float* __restrict__ deg) {
    int i = blockIdx.x * blockDim.x + threadIdx.x;
    if (i < EE) atomicAdd(&deg[col[i]], 1.0f);
}

__global__ void k_reduce(const float* __restrict__ e, float* __restrict__ out,
                         const float* __restrict__ meanptr) {
    float mean = meanptr ? (*meanptr) / (float)NN : 0.0f;
    float s = 0.f;
    for (int i = blockIdx.x * blockDim.x + threadIdx.x; i < NN; i += gridDim.x * blockDim.x) {
        if (meanptr) { float v = e[i] - mean; s += v * v; }
        else s += e[i];
    }
    s = wave_sum(s);
    __shared__ float ls[4];
    int lane = threadIdx.x & 63, w = threadIdx.x >> 6;
    if (lane == 0) ls[w] = s;
    __syncthreads();
    if (threadIdx.x == 0) atomicAdd(out, ls[0] + ls[1] + ls[2] + ls[3]);
}

__global__ void k_standardize(float* __restrict__ e, const float* __restrict__ scal) {
    float mean = scal[0] / (float)NN;
    float var = scal[1] / (float)(NN - 1);
    float inv = 1.0f / (sqrtf(var) + 1e-6f);
    int i = blockIdx.x * blockDim.x + threadIdx.x;
    if (i < NN) e[i] = (e[i] - mean) * inv;
}

// ---- tiny energy-branch MLP: 1 -> 16 relu -> 8, bf16 out ----
__global__ void k_pe(const float* __restrict__ e, const float* __restrict__ w1,
                     const float* __restrict__ b1, const float* __restrict__ w2,
                     const float* __restrict__ b2, unsigned short* __restrict__ pe, int M) {
    int i = blockIdx.x * blockDim.x + threadIdx.x;
    if (i >= M) return;
    float ev = e[i];
    float h[16];
    #pragma unroll
    for (int j = 0; j < 16; ++j) h[j] = fmaxf(ev * w1[j] + b1[j], 0.f);
    #pragma unroll
    for (int k = 0; k < 8; ++k) {
        float s = b2[k];
        #pragma unroll
        for (int j = 0; j < 16; ++j) s += h[j] * w2[j * 8 + k];
        pe[(size_t)i * 8 + k] = f2b(s);
    }
}

__global__ void k_dis(const float* __restrict__ deg, float* __restrict__ dis) {
    int i = blockIdx.x * blockDim.x + threadIdx.x;
    if (i < NN) dis[i] = 1.0f / sqrtf(deg[i] + 1.0f);
}

// ---- CSR build: block-wise exclusive scan of degrees ----
__global__ void k_scan_block(const float* __restrict__ deg, int* __restrict__ offs,
                             int* __restrict__ bsum) {
    __shared__ int s[256];
    int t = threadIdx.x;
    int base = blockIdx.x * 1024 + t * 4;
    int v0 = (base + 0 < NN) ? (int)deg[base + 0] : 0;
    int v1 = (base + 1 < NN) ? (int)deg[base + 1] : 0;
    int v2 = (base + 2 < NN) ? (int)deg[base + 2] : 0;
    int v3 = (base + 3 < NN) ? (int)deg[base + 3] : 0;
    int lsum = v0 + v1 + v2 + v3;
    s[t] = lsum;
    __syncthreads();
    for (int off = 1; off < 256; off <<= 1) {
        int x = (t >= off) ? s[t - off] : 0;
        __syncthreads();
        s[t] += x;
        __syncthreads();
    }
    if (t == 255) bsum[blockIdx.x] = s[255];
    int run = s[t] - lsum;
    if (base + 0 < NN) offs[base + 0] = run; run += v0;
    if (base + 1 < NN) offs[base + 1] = run; run += v1;
    if (base + 2 < NN) offs[base + 2] = run; run += v2;
    if (base + 3 < NN) offs[base + 3] = run;
}
__global__ void k_scan_tops(int* __restrict__ bsum, int nb) {
    if (blockIdx.x == 0 && threadIdx.x == 0) {
        int acc = 0;
        for (int i = 0; i < nb; ++i) { int t = bsum[i]; bsum[i] = acc; acc += t; }
    }
}
__global__ void k_scan_add(int* __restrict__ offs, const int* __restrict__ bsum) {
    int i = blockIdx.x * blockDim.x + threadIdx.x;
    if (i < NN) offs[i] += bsum[i >> 10];
}
__global__ void k_scatter(const int* __restrict__ row, const int* __restrict__ col,
                          const float* __restrict__ dis, const int* __restrict__ offs,
                          int* __restrict__ cnt, int* __restrict__ crows,
                          float* __restrict__ cnrm) {
    int e = blockIdx.x * blockDim.x + threadIdx.x;
    if (e >= EE) return;
    int c = col[e], r = row[e];
    int p = offs[c] + atomicAdd(&cnt[c], 1);
    crows[p] = r;
    cnrm[p] = dis[r] * dis[c];
}

// ---- belief propagation via CSR gather (e is 400KB, L2-resident), unroll-4 ----
__global__ void k_bprop(const int* __restrict__ offs, const float* __restrict__ degv,
                        const int* __restrict__ crows, const float* __restrict__ ein,
                        float* __restrict__ eout) {
    int i = blockIdx.x * blockDim.x + threadIdx.x;
    if (i >= NN) return;
    int s = offs[i];
    int d = (int)degv[i];
    int eN = s + d;
    float sum = 0.f;
    int ei = s;
    for (; ei + 4 <= eN; ei += 4) {
        float v0 = ein[crows[ei]];
        float v1 = ein[crows[ei + 1]];
        float v2 = ein[crows[ei + 2]];
        float v3 = ein[crows[ei + 3]];
        sum += v0 + v1 + v2 + v3;
    }
    for (; ei < eN; ++ei) sum += ein[crows[ei]];
    float aggv = d > 0 ? sum / (float)d : 0.f;
    eout[i] = 0.5f * ein[i] + 0.5f * aggv;
}

// ---- GCN aggregation: one wave per node, bf16 h in, bf16 g out, unroll-4 MLP ----
__global__ void k_gagg(const int* __restrict__ offs, const float* __restrict__ degv,
                       const int* __restrict__ crows, const float* __restrict__ cnrm,
                       const unsigned short* __restrict__ hb, const float* __restrict__ dis,
                       const float* __restrict__ gcn_b, unsigned short* __restrict__ gb) {
    int wid = (int)((blockIdx.x * (size_t)blockDim.x + threadIdx.x) >> 6);
    int lane = threadIdx.x & 63;
    if (wid >= NN) return;
    int s = offs[wid], eN = s + (int)degv[wid];
    float a0 = 0.f, a1 = 0.f;
    int ei = s;
    for (; ei + 4 <= eN; ei += 4) {
        int r0 = crows[ei], r1 = crows[ei + 1], r2 = crows[ei + 2], r3 = crows[ei + 3];
        float n0 = cnrm[ei], n1 = cnrm[ei + 1], n2 = cnrm[ei + 2], n3 = cnrm[ei + 3];
        unsigned p0 = *(const unsigned*)(hb + (size_t)r0 * CC + 2 * lane);
        unsigned p1 = *(const unsigned*)(hb + (size_t)r1 * CC + 2 * lane);
        unsigned p2 = *(const unsigned*)(hb + (size_t)r2 * CC + 2 * lane);
        unsigned p3 = *(const unsigned*)(hb + (size_t)r3 * CC + 2 * lane);
        a0 += n0 * b2f_lo(p0) + n1 * b2f_lo(p1) + n2 * b2f_lo(p2) + n3 * b2f_lo(p3);
        a1 += n0 * b2f_hi(p0) + n1 * b2f_hi(p1) + n2 * b2f_hi(p2) + n3 * b2f_hi(p3);
    }
    for (; ei < eN; ++ei) {
        int r = crows[ei];
        float nr = cnrm[ei];
        unsigned pv = *(const unsigned*)(hb + (size_t)r * CC + 2 * lane);
        a0 += nr * b2f_lo(pv);
        a1 += nr * b2f_hi(pv);
    }
    float dd = dis[wid] * dis[wid];
    unsigned sv = *(const unsigned*)(hb + (size_t)wid * CC + 2 * lane);
    float g0 = gcn_b[2 * lane]     + dd * b2f_lo(sv) + a0;
    float g1 = gcn_b[2 * lane + 1] + dd * b2f_hi(sv) + a1;
    unsigned op = ((unsigned)f2b(g1) << 16) | (unsigned)f2b(g0);
    *(unsigned*)(gb + (size_t)wid * CC + 2 * lane) = op;
}

// ---- f32 weight [K][N] -> bf16 TRANSPOSED [N][KP], zero-padded k>=K ----
__global__ void k_w2bt(const float* __restrict__ src, unsigned short* __restrict__ dst,
                       int K, int N, int KP) {
    int i = blockIdx.x * blockDim.x + threadIdx.x;
    if (i >= N * KP) return;
    int n = i / KP, k = i - n * KP;
    dst[i] = (k < K) ? f2b(src[(size_t)k * N + n]) : (unsigned short)0;
}

// ---- weight fusion 1: W' = fp_w2(512x256) @ gcn_w(256x128) -> wT[128][512] bf16;
//      b'[n] = fp_b2 @ gcn_w  (f32) ----
__global__ void k_wf1(const float* __restrict__ fp_w2, const float* __restrict__ fp_b2,
                      const float* __restrict__ gcn_w, unsigned short* __restrict__ wT,
                      float* __restrict__ bf) {
    int i = blockIdx.x * blockDim.x + threadIdx.x;
    if (i >= 512 * 128) return;
    int k = i >> 7, n = i & 127;
    float s = 0.f;
    for (int j = 0; j < 256; ++j) s += fp_w2[(size_t)k * 128 * 2 + j] * 0.f; // placeholder avoided below
    // recompute properly (fp_w2 is [512][256]):
    s = 0.f;
    for (int j = 0; j < 256; ++j) s += fp_w2[(size_t)k * 256 + j] * gcn_w[(size_t)j * 128 + n];
    wT[(size_t)n * 512 + k] = f2b(s);
    if (k == 0) {
        float b = 0.f;
        for (int j = 0; j < 256; ++j) b += fp_b2[j] * gcn_w[(size_t)j * 128 + n];
        bf[n] = b;
    }
}

// ---- weight fusion 2: Wx' = gt_w(128x256) @ af_xw(256x193) -> wT[193][128] bf16;
//      bx'[n] = gt_b @ af_xw + af_xb  (f32) ----
__global__ void k_wf2(const float* __restrict__ gt_w, const float* __restrict__ gt_b,
                      const float* __restrict__ af_xw, const float* __restrict__ af_xb,
                      unsigned short* __restrict__ wT, float* __restrict__ bx) {
    int i = blockIdx.x * blockDim.x + threadIdx.x;
    if (i >= NFD * 128) return;
    int n = i >> 7, k = i & 127;
    float s = 0.f;
    for (int j = 0; j < 256; ++j) s += gt_w[(size_t)k * 256 + j] * af_xw[(size_t)j * NFD + n];
    wT[(size_t)n * 128 + k] = f2b(s);
    if (k == 0) {
        float b = af_xb[n];
        for (int j = 0; j < 256; ++j) b += gt_b[j] * af_xw[(size_t)j * NFD + n];
        bx[n] = b;
    }
}

// ---- bf16 MFMA GEMM: C = act(A[MxK] @ W[KxN] + bias), W given TRANSPOSED [N][KP] ----
__global__ __launch_bounds__(256) void k_mgemm(
    const void* __restrict__ Ap, const int aF32, const int lda,
    const unsigned short* __restrict__ BT, const int ldbt,
    const float* __restrict__ bias, void* __restrict__ Cp,
    const int outBf16, const int M, const int K, const int N, const int act)
{
    __shared__ unsigned short As[128][40];
    __shared__ unsigned short Bs[128][40];
    int t = threadIdx.x;
    int lane = t & 63, wv = t >> 6;
    int wm = wv >> 1, wn = wv & 1;
    int rowBase = blockIdx.y * 128, colBase = blockIdx.x * 128;
    const float* Af = (const float*)Ap;
    const unsigned short* Ah = (const unsigned short*)Ap;
    f32x4 acc[4][4] = {};
    int kg = lane >> 4, rc = lane & 15;

    for (int kk = 0; kk < K; kk += 32) {
        #pragma unroll
        for (int vi = 0; vi < 2; ++vi) {
            int v = t + vi * 256;
            int r = v >> 2, c8 = (v & 3) * 8;
            int gr = rowBase + r, gk = kk + c8;
            unsigned short tmp[8];
            if (gr < M && gk + 8 <= K) {
                if (aF32) {
                    const float* p = Af + (size_t)gr * lda + gk;
                    float4 fa = *(const float4*)p;
                    float4 fb = *(const float4*)(p + 4);
                    tmp[0] = f2b(fa.x); tmp[1] = f2b(fa.y); tmp[2] = f2b(fa.z); tmp[3] = f2b(fa.w);
                    tmp[4] = f2b(fb.x); tmp[5] = f2b(fb.y); tmp[6] = f2b(fb.z); tmp[7] = f2b(fb.w);
                } else {
                    *(short8*)tmp = *(const short8*)(Ah + (size_t)gr * lda + gk);
                }
            } else {
                #pragma unroll
                for (int j = 0; j < 8; ++j) {
                    int k2 = gk + j;
                    unsigned short hv = 0;
                    if (gr < M && k2 < K)
                        hv = aF32 ? f2b(Af[(size_t)gr * lda + k2]) : Ah[(size_t)gr * lda + k2];
                    tmp[j] = hv;
                }
            }
            *(short8*)&As[r][c8] = *(short8*)tmp;
        }
        #pragma unroll
        for (int vi = 0; vi < 2; ++vi) {
            int v = t + vi * 256;
            int r = v >> 2, c8 = (v & 3) * 8;
            int gn = colBase + r, gk = kk + c8;
            unsigned short tmp[8];
            if (gn < N) {
                *(short8*)tmp = *(const short8*)(BT + (size_t)gn * ldbt + gk);
            } else {
                #pragma unroll
                for (int j = 0; j < 8; ++j) tmp[j] = 0;
            }
            *(short8*)&Bs[r][c8] = *(short8*)tmp;
        }
        __syncthreads();
        short8 afr[4], bfr[4];
        #pragma unroll
        for (int i = 0; i < 4; ++i) {
            afr[i] = *(const short8*)&As[wm * 64 + i * 16 + rc][kg * 8];
            bfr[i] = *(const short8*)&Bs[wn * 64 + i * 16 + rc][kg * 8];
        }
        #pragma unroll
        for (int i = 0; i < 4; ++i)
            #pragma unroll
            for (int j = 0; j < 4; ++j)
                acc[i][j] = __builtin_amdgcn_mfma_f32_16x16x32_bf16(afr[i], bfr[j], acc[i][j], 0, 0, 0);
        __syncthreads();
    }

    float* Cf = (float*)Cp;
    unsigned short* Ch = (unsigned short*)Cp;
    #pragma unroll
    for (int j = 0; j < 4; ++j) {
        int gc = colBase + wn * 64 + j * 16 + rc;
        if (gc >= N) continue;
        float bv = bias ? bias[gc] : 0.f;
        #pragma unroll
        for (int i = 0; i < 4; ++i) {
            #pragma unroll
            for (int q = 0; q < 4; ++q) {
                int gr = rowBase + wm * 64 + i * 16 + kg * 4 + q;
                if (gr >= M) continue;
                float vv = acc[i][j][q] + bv;
                if (act) vv = fmaxf(vv, 0.f);
                if (outBf16) Ch[(size_t)gr * N + gc] = f2b(vv);
                else         Cf[(size_t)gr * N + gc] = vv;
            }
        }
    }
}

// ---- attention fusion: f32 in (stride NFD), bf16 fused out (stride NFP) ----
__global__ void k_fuse(const float* __restrict__ xt, const float* __restrict__ lt,
                       const float* __restrict__ et, const float* __restrict__ aw,
                       const float* __restrict__ ab, unsigned short* __restrict__ fo, int M) {
    int wid = (int)((blockIdx.x * blockDim.x + threadIdx.x) >> 6);
    int lane = threadIdx.x & 63;
    if (wid >= M) return;
    size_t base = (size_t)wid * NFD;
    float xv[4], lv[4], ev[4];
    float dx = 0.f, dl = 0.f, de = 0.f;
    #pragma unroll
    for (int q = 0; q < 4; ++q) {
        int j = q * 64 + lane;
        bool ok = j < NFD;
        float awv = ok ? aw[j] : 0.f;
        xv[q] = ok ? xt[base + j] : 0.f;
        lv[q] = ok ? lt[base + j] : 0.f;
        ev[q] = ok ? et[base + j] : 0.f;
        dx += xv[q] * awv; dl += lv[q] * awv; de += ev[q] * awv;
    }
    dx = wave_sum(dx); dl = wave_sum(dl); de = wave_sum(de);
    float abv = ab[0];
    float sx = 1.f / (1.f + expf(-(dx + abv)));
    float sl = 1.f / (1.f + expf(-(dl + abv)));
    float se = 1.f / (1.f + expf(-(de + abv)));
    float inv = 1.f / (sx + sl + se);
    #pragma unroll
    for (int q = 0; q < 4; ++q) {
        int j = q * 64 + lane;
        if (j < NFD) fo[(size_t)wid * NFP + j] = f2b((sx * xv[q] + sl * lv[q] + se * ev[q]) * inv);
    }
}

__global__ void k_pred(const float* __restrict__ h2, const float* __restrict__ w3,
                       const float* __restrict__ b3, float* __restrict__ pred, int M) {
    int wid = (int)((blockIdx.x * blockDim.x + threadIdx.x) >> 6);
    int lane = threadIdx.x & 63;
    if (wid >= M) return;
    const float* r = h2 + (size_t)wid * CC;
    float s = r[lane] * w3[lane] + r[lane + 64] * w3[lane + 64];
    s = wave_sum(s);
    if (lane == 0) pred[wid] = 1.f / (1.f + expf(-(s + b3[0])));
}

__global__ void k_gather(const float* __restrict__ pred, const int* __restrict__ mask,
                         float* __restrict__ out, int n) {
    int i = blockIdx.x * blockDim.x + threadIdx.x;
    if (i < n) out[i] = pred[mask[i]];
}

static inline void mgemm(const void* A, int aF32, int lda, const unsigned short* BT, int ldbt,
                         const float* bias, void* C, int outBf16,
                         int M, int K, int N, int act, hipStream_t s) {
    dim3 grid((N + 127) / 128, (M + 127) / 128);
    k_mgemm<<<grid, 256, 0, s>>>(A, aF32, lda, BT, ldbt, bias, C, outBf16, M, K, N, act);
}

extern "C" void kernel_launch(void* const* d_in, const int* in_sizes, int n_in,
                              void* d_out, int out_size, void* d_ws, size_t ws_size,
                              hipStream_t stream) {
    const float* logits = (const float*)d_in[0];
    const float* x      = (const float*)d_in[1];
    const int*   eidx   = (const int*)d_in[2];
    const int*   mask   = (const int*)d_in[3];
    const float* fp_w1 = (const float*)d_in[4];
    const float* fp_b1 = (const float*)d_in[5];
    const float* fp_w2 = (const float*)d_in[6];
    const float* fp_b2 = (const float*)d_in[7];
    const float* ep_w1 = (const float*)d_in[8];
    const float* ep_b1 = (const float*)d_in[9];
    const float* ep_w2 = (const float*)d_in[10];
    const float* ep_b2 = (const float*)d_in[11];
    const float* lp_w1 = (const float*)d_in[12];
    const float* lp_b1 = (const float*)d_in[13];
    const float* lp_w2 = (const float*)d_in[14];
    const float* lp_b2 = (const float*)d_in[15];
    const float* gcn_w = (const float*)d_in[16];
    const float* gcn_b = (const float*)d_in[17];
    const float* gt_w  = (const float*)d_in[18];
    const float* gt_b  = (const float*)d_in[19];
    const float* af_xw = (const float*)d_in[20];
    const float* af_xb = (const float*)d_in[21];
    const float* af_lw = (const float*)d_in[22];
    const float* af_lb = (const float*)d_in[23];
    const float* af_ew = (const float*)d_in[24];
    const float* af_eb = (const float*)d_in[25];
    const float* af_aw = (const float*)d_in[26];
    const float* af_ab = (const float*)d_in[27];
    const float* fu_w1 = (const float*)d_in[28];
    const float* fu_b1 = (const float*)d_in[29];
    const float* fu_w2 = (const float*)d_in[30];
    const float* fu_b2 = (const float*)d_in[31];
    const float* fu_w3 = (const float*)d_in[32];
    const float* fu_b3 = (const float*)d_in[33];
    const int* row = eidx;
    const int* col = eidx + EE;
    float* out = (float*)d_out;

    // ---- fixed workspace (~67 MB) ----
    char* wsb = (char*)d_ws;
    size_t o = 0;
    auto alloc = [&](size_t bytes) { char* p = wsb + o; o += (bytes + 255) & ~(size_t)255; return p; };
    float* e_   = (float*)alloc((size_t)NN * 4);
    float* degv = (float*)alloc((size_t)NN * 4);
    float* agg  = (float*)alloc((size_t)NN * 4);   // BP ping-pong; later pred
    float* dis  = (float*)alloc((size_t)NN * 4);
    float* scal = (float*)alloc(64);
    int*   offs = (int*)alloc((size_t)(NN + 4) * 4);
    int*   cnt  = (int*)alloc((size_t)NN * 4);
    int*   bsum = (int*)alloc(512);
    int*   crows= (int*)alloc((size_t)EE * 4);
    float* cnrm = (float*)alloc((size_t)EE * 4);
    unsigned short* hb = (unsigned short*)alloc((size_t)NN * CC * 2);  // bf16 h
    unsigned short* gb = (unsigned short*)alloc((size_t)NN * CC * 2);  // bf16 g
    // transposed bf16 weights [N][KP]
    unsigned short* wfp1T = (unsigned short*)alloc((size_t)512 * 256 * 2);
    unsigned short* wfhT  = (unsigned short*)alloc((size_t)128 * 512 * 2);  // fused fp_w2@gcn_w
    unsigned short* wlp1T = (unsigned short*)alloc((size_t)128 * 128 * 2);
    unsigned short* wlp2T = (unsigned short*)alloc((size_t)64 * 128 * 2);
    unsigned short* wxT   = (unsigned short*)alloc((size_t)NFD * 128 * 2);  // fused gt_w@af_xw
    unsigned short* waflT = (unsigned short*)alloc((size_t)NFD * 64 * 2);
    unsigned short* wafeT = (unsigned short*)alloc((size_t)NFD * 32 * 2);
    unsigned short* wfu1T = (unsigned short*)alloc((size_t)256 * 224 * 2);
    unsigned short* wfu2T = (unsigned short*)alloc((size_t)128 * 256 * 2);
    float* bfh = (float*)alloc(128 * 4);   // fused h bias
    float* bx2 = (float*)alloc(NFD * 4);   // fused xt bias
    size_t fixed = o;

    // ---- chunk area: 4152 B/row (Phase B); Phase A needs 1024 and aliases it ----
    const size_t SROW = 4152;
    size_t rem = (ws_size > fixed) ? ws_size - fixed : 0;
    size_t chq = rem / SROW;
    int CH = (chq >= (size_t)NN) ? NN : (int)chq;
    CH &= ~1;                      // keep offsets 16B-aligned
    if (CH < 2) CH = 2;
    char* cb = wsb + fixed;
    int nch = (NN + CH - 1) / CH;

    hipMemsetAsync(degv, 0, (size_t)NN * 4, stream);
    hipMemsetAsync(scal, 0, 64, stream);
    hipMemsetAsync(cnt,  0, (size_t)NN * 4, stream);

    // ---- energy + degrees + CSR ----
    k_energy<<<(NN + 3) / 4, 256, 0, stream>>>(logits, e_);
    k_deg<<<(EE + 255) / 256, 256, 0, stream>>>(col, degv);
    k_dis<<<(NN + 255) / 256, 256, 0, stream>>>(degv, dis);
    int nb = (NN + 1023) / 1024;
    k_scan_block<<<nb, 256, 0, stream>>>(degv, offs, bsum);
    k_scan_tops<<<1, 64, 0, stream>>>(bsum, nb);
    k_scan_add<<<(NN + 255) / 256, 256, 0, stream>>>(offs, bsum);
    k_scatter<<<(EE + 255) / 256, 256, 0, stream>>>(row, col, dis, offs, cnt, crows, cnrm);

    // ---- belief propagation (CSR gather, 2 iterations, ping-pong) ----
    k_bprop<<<(NN + 255) / 256, 256, 0, stream>>>(offs, degv, crows, e_, agg);
    k_bprop<<<(NN + 255) / 256, 256, 0, stream>>>(offs, degv, crows, agg, e_);
    k_reduce<<<256, 256, 0, stream>>>(e_, &scal[0], nullptr);
    k_reduce<<<256, 256, 0, stream>>>(e_, &scal[1], &scal[0]);
    k_standardize<<<(NN + 255) / 256, 256, 0, stream>>>(e_, scal);

    // ---- weights: transpose + fuse ----
    auto w2bt = [&](const float* s, unsigned short* d, int K, int N, int KP) {
        int tot = N * KP;
        k_w2bt<<<(tot + 255) / 256, 256, 0, stream>>>(s, d, K, N, KP);
    };
    w2bt(fp_w1, wfp1T, 256, 512, 256);
    w2bt(lp_w1, wlp1T, 128, 128, 128);
    w2bt(lp_w2, wlp2T, 128, 64, 128);
    w2bt(af_lw, waflT, 64,  NFD, 64);
    w2bt(af_ew, wafeT, 8,   NFD, 32);
    w2bt(fu_w1, wfu1T, NFD, 256, 224);
    w2bt(fu_w2, wfu2T, 256, 128, 256);
    k_wf1<<<(512 * 128 + 255) / 256, 256, 0, stream>>>(fp_w2, fp_b2, gcn_w, wfhT, bfh);
    k_wf2<<<(NFD * 128 + 255) / 256, 256, 0, stream>>>(gt_w, gt_b, af_xw, af_xb, wxT, bx2);

    // ---- Phase A (chunked): x -> hid -> h(bf16) directly (fused weights) ----
    for (int c = 0; c < nch; ++c) {
        int base = c * CH;
        int m = (NN - base < CH) ? (NN - base) : CH;
        unsigned short* hid = (unsigned short*)cb;                       // 1024B/row
        mgemm(x + (size_t)base * FF, 1, 256, wfp1T, 256, fp_b1, hid, 1, m, 256, 512, 1, stream);
        mgemm(hid, 0, 512, wfhT, 512, bfh, hb + (size_t)base * CC, 1, m, 512, 128, 0, stream);
    }

    // ---- GCN aggregation (gather, unroll-4, bf16 in/out) ----
    k_gagg<<<(int)(((size_t)NN * 64 + 255) / 256), 256, 0, stream>>>(
        offs, degv, crows, cnrm, hb, dis, gcn_b, gb);

    // ---- Phase B (chunked) ----
    for (int c = 0; c < nch; ++c) {
        int base = c * CH;
        int m = (NN - base < CH) ? (NN - base) : CH;
        unsigned short* lph = (unsigned short*)cb;                         // [0,256)
        unsigned short* pl  = (unsigned short*)(cb + (size_t)256 * CH);    // [256,384)
        unsigned short* peb = (unsigned short*)(cb + (size_t)384 * CH);    // [384,400)
        float* xt  = (float*)(cb + (size_t)400 * CH);                      // [400,1176)
        float* lt  = (float*)(cb + (size_t)1176 * CH);                     // [1176,1952)
        float* et  = (float*)(cb + (size_t)1952 * CH);                     // [1952,2728)
        unsigned short* fus = (unsigned short*)(cb + (size_t)2728 * CH);   // [2728,3128) stride NFP
        unsigned short* h1  = (unsigned short*)(cb + (size_t)3128 * CH);   // [3128,3640)
        float* h2  = (float*)(cb + (size_t)3640 * CH);                     // [3640,4152)

        mgemm(logits + (size_t)base * CC, 1, 128, wlp1T, 128, lp_b1, lph, 1, m, 128, 128, 1, stream);
        mgemm(lph, 0, 128, wlp2T, 128, lp_b2, pl, 1, m, 128, 64, 0, stream);
        k_pe<<<(m + 255) / 256, 256, 0, stream>>>(e_ + base, ep_w1, ep_b1, ep_w2, ep_b2, peb, m);

        mgemm(gb + (size_t)base * CC, 0, 128, wxT, 128, bx2, xt, 0, m, 128, NFD, 0, stream);
        mgemm(pl, 0, 64, waflT, 64, af_lb, lt, 0, m, 64, NFD, 0, stream);
        mgemm(peb, 0, 8, wafeT, 32, af_eb, et, 0, m, 8, NFD, 0, stream);
        k_fuse<<<(m + 3) / 4, 256, 0, stream>>>(xt, lt, et, af_aw, af_ab, fus, m);

        mgemm(fus, 0, NFP, wfu1T, 224, fu_b1, h1, 1, m, NFD, 256, 1, stream);
        mgemm(h1, 0, 256, wfu2T, 256, fu_b2, h2, 0, m, 256, 128, 1, stream);
        k_pred<<<(m + 3) / 4, 256, 0, stream>>>(h2, fu_w3, fu_b3, agg + base, m);
    }

    k_gather<<<(out_size + 255) / 256, 256, 0, stream>>>(agg, mask, out, out_size);
}